// Round 1
// baseline (6345.675 us; speedup 1.0000x reference)
//
#include <hip/hip_runtime.h>
#include <math.h>

#define DIMC 128
#define NH 8
#define HDC 16

// ---------------------------------------------------------------- QKV ------
__global__ __launch_bounds__(128)
void qkv_kernel(const float* __restrict__ h,
                const float* __restrict__ Wq, const float* __restrict__ Wk,
                const float* __restrict__ Wv,
                float* __restrict__ Qb, float* __restrict__ Kb, float* __restrict__ Vb)
{
    __shared__ float hl[16 * 128];
    const int t  = threadIdx.x;
    const int n0 = blockIdx.x * 16;

    const float4* hg4 = (const float4*)(h + (size_t)n0 * 128);
    float4* hl4 = (float4*)hl;
    #pragma unroll
    for (int i = 0; i < 4; ++i) hl4[i * 128 + t] = hg4[i * 128 + t];
    __syncthreads();

    #pragma unroll
    for (int m = 0; m < 3; ++m) {
        const float* W = (m == 0 ? Wq : (m == 1 ? Wk : Wv)) + t * 128;
        float*       o = (m == 0 ? Qb : (m == 1 ? Kb : Vb)) + (size_t)n0 * 128 + t;
        float acc[16];
        #pragma unroll
        for (int n = 0; n < 16; ++n) acc[n] = 0.f;
        for (int kc = 0; kc < 32; ++kc) {
            const float4 w = *(const float4*)(W + kc * 4);
            #pragma unroll
            for (int n = 0; n < 16; ++n) {
                const float4 x = *(const float4*)&hl[n * 128 + kc * 4];
                acc[n] += w.x * x.x + w.y * x.y + w.z * x.z + w.w * x.w;
            }
        }
        #pragma unroll
        for (int n = 0; n < 16; ++n) o[(size_t)n * 128] = acc[n];
    }
}

// ---------------------------------------------------------------- EDGE -----
// Per block: stage WeT (swizzled) once, then 4 tiles of 32 edges.
// Thread tile: 2 edges x 8 dims. 256 threads = 16 edge-groups x 16 dim-groups.
__global__ __launch_bounds__(256)
void edge_kernel(const int* __restrict__ ei, const float* __restrict__ eattr,
                 const float* __restrict__ We, const float* __restrict__ Wb,
                 const float* __restrict__ bbv,
                 const float* __restrict__ Qb, const float* __restrict__ Kb,
                 const float* __restrict__ Vb,
                 float* __restrict__ wV, float* __restrict__ Zb, int EDG)
{
    __shared__ float WeT[128 * 128];   // 64 KB, element (k,d) at k*128 + (d ^ ((k&7)<<2))
    __shared__ float WbT[128 * 8];     // 4 KB,  (k,h) at k*8 + h
    __shared__ float eaT[128 * 32];    // 16 KB, (k,e) at k*32 + (e ^ (k&30))
    __shared__ float Gl[32 * 132];     // K[src]*Q[dst], padded stride 132
    __shared__ float Vl[32 * 132];     // V[src], padded stride 132
    __shared__ int   sdst[32];

    const int t = threadIdx.x;

    // ---- stage WeT (coalesced global read, 8-way-swizzled LDS write) ----
    for (int i = 0; i < 64; ++i) {
        int idx = i * 256 + t;
        int d = idx >> 7, k = idx & 127;
        WeT[k * 128 + (d ^ ((k & 7) << 2))] = We[idx];
    }
    // ---- stage WbT ----
    #pragma unroll
    for (int i = 0; i < 4; ++i) {
        int idx = i * 256 + t;
        int hh2 = idx >> 7, k = idx & 127;
        WbT[k * 8 + hh2] = Wb[idx];
    }

    const int eg = t >> 4;          // 0..15 edge-group (2 edges)
    const int dg = t & 15;          // 0..15 dim-group (8 dims)
    const int p0 = dg * 8;
    const int hh = dg >> 1;         // head of this dim-group
    const float bias = bbv[hh];
    const int le = t >> 3, lj = t & 7;   // loader roles: 32 edges x 8 threads

    for (int tile = 0; tile < 4; ++tile) {
        __syncthreads();            // protect LDS reuse (also orders WeT staging)
        const int e0 = (blockIdx.x * 4 + tile) * 32;

        // ---- stage G = K[src]*Q[dst], V[src], dst, eaT ----
        {
            const int eg2 = e0 + le;
            const int s    = ei[eg2];
            const int dsti = ei[EDG + eg2];
            if (lj == 0) sdst[le] = dsti;
            #pragma unroll
            for (int i = 0; i < 4; ++i) {
                const int d = lj * 16 + i * 4;
                const float4 kk = *(const float4*)&Kb[(size_t)s * 128 + d];
                const float4 qq = *(const float4*)&Qb[(size_t)dsti * 128 + d];
                const float4 vv = *(const float4*)&Vb[(size_t)s * 128 + d];
                float4 g;
                g.x = kk.x * qq.x; g.y = kk.y * qq.y; g.z = kk.z * qq.z; g.w = kk.w * qq.w;
                *(float4*)&Gl[le * 132 + d] = g;
                *(float4*)&Vl[le * 132 + d] = vv;
            }
            for (int i = 0; i < 16; ++i) {
                int flat = i * 256 + t;
                int ee = flat >> 7, k = flat & 127;
                eaT[k * 32 + (ee ^ (k & 30))] = eattr[(size_t)(e0 + ee) * 128 + k];
            }
        }
        __syncthreads();

        // ---- fused E-GEMM (+ E_bias dot) ----
        float eacc[16];
        #pragma unroll
        for (int j = 0; j < 16; ++j) eacc[j] = 0.f;
        float eb0 = 0.f, eb1 = 0.f;
        #pragma unroll 2
        for (int k = 0; k < 128; ++k) {
            const int xk = (k & 7) << 2;
            const float2 ea2 = *(const float2*)&eaT[k * 32 + ((eg * 2) ^ (k & 30))];
            const float  wbv = WbT[k * 8 + hh];
            const float4 w0  = *(const float4*)&WeT[k * 128 + (p0 ^ xk)];
            const float4 w1  = *(const float4*)&WeT[k * 128 + ((p0 + 4) ^ xk)];
            eacc[0]  += ea2.x * w0.x; eacc[1]  += ea2.x * w0.y;
            eacc[2]  += ea2.x * w0.z; eacc[3]  += ea2.x * w0.w;
            eacc[4]  += ea2.x * w1.x; eacc[5]  += ea2.x * w1.y;
            eacc[6]  += ea2.x * w1.z; eacc[7]  += ea2.x * w1.w;
            eacc[8]  += ea2.y * w0.x; eacc[9]  += ea2.y * w0.y;
            eacc[10] += ea2.y * w0.z; eacc[11] += ea2.y * w0.w;
            eacc[12] += ea2.y * w1.x; eacc[13] += ea2.y * w1.y;
            eacc[14] += ea2.y * w1.z; eacc[15] += ea2.y * w1.w;
            eb0 += ea2.x * wbv; eb1 += ea2.y * wbv;
        }

        // ---- score: per-head reduce across dg twins ----
        const int ea0 = eg * 2, ea1 = eg * 2 + 1;
        float sp0 = 0.f, sp1 = 0.f;
        #pragma unroll
        for (int j = 0; j < 8; ++j) {
            sp0 += Gl[ea0 * 132 + p0 + j] * eacc[j];
            sp1 += Gl[ea1 * 132 + p0 + j] * eacc[8 + j];
        }
        sp0 += __shfl_xor(sp0, 1, 64);
        sp1 += __shfl_xor(sp1, 1, 64);
        float s0 = sp0 * 0.25f + eb0 + bias;
        float s1 = sp1 * 0.25f + eb1 + bias;
        s0 = expf(fminf(fmaxf(s0, -5.f), 5.f));
        s1 = expf(fminf(fmaxf(s1, -5.f), 5.f));

        // ---- scatter messages ----
        const int dst0 = sdst[ea0], dst1 = sdst[ea1];
        #pragma unroll
        for (int j = 0; j < 8; ++j) {
            atomicAdd(&wV[(size_t)dst0 * 128 + p0 + j], Vl[ea0 * 132 + p0 + j] * s0);
            atomicAdd(&wV[(size_t)dst1 * 128 + p0 + j], Vl[ea1 * 132 + p0 + j] * s1);
        }
        if ((dg & 1) == 0) {
            atomicAdd(&Zb[(size_t)dst0 * 8 + hh], s0);
            atomicAdd(&Zb[(size_t)dst1 * 8 + hh], s1);
        }
    }
}

// --------------------------------------------- residual + BN1 stats --------
__global__ __launch_bounds__(256)
void resid_stats(const float* __restrict__ h, const float* __restrict__ wV,
                 const float* __restrict__ Zb, float* __restrict__ x,
                 float* __restrict__ stat, int total)
{
    const int t = threadIdx.x;
    float s = 0.f, sq = 0.f;
    const int stride = gridDim.x * blockDim.x;
    for (int i = blockIdx.x * blockDim.x + t; i < total; i += stride) {
        const float z = Zb[(i >> 7) * 8 + ((i & 127) >> 4)];
        const float v = h[i] + wV[i] / (z + 1e-6f);
        x[i] = v; s += v; sq += v * v;
    }
    __shared__ float ls[256], lq[256];
    ls[t] = s; lq[t] = sq;
    __syncthreads();
    if (t < 128) {
        atomicAdd(&stat[t],       ls[t] + ls[t + 128]);
        atomicAdd(&stat[128 + t], lq[t] + lq[t + 128]);
    }
}

// ---------------------------------------------------------- BN params ------
__global__ void bn_params(const float* __restrict__ sum, const float* __restrict__ sumsq,
                          const float* __restrict__ gamma, const float* __restrict__ beta,
                          float* __restrict__ a, float* __restrict__ b, float invn)
{
    const int c = threadIdx.x;
    const float mean = sum[c] * invn;
    const float var  = sumsq[c] * invn - mean * mean;
    const float sc   = gamma[c] * rsqrtf(var + 1e-5f);
    a[c] = sc;
    b[c] = beta[c] - mean * sc;
}

// ---------------------------------------------------------------- FFN ------
__global__ __launch_bounds__(128)
void ffn_kernel(const float* __restrict__ x, const float* __restrict__ W1,
                const float* __restrict__ b1, const float* __restrict__ W2,
                const float* __restrict__ b2, const float* __restrict__ par,
                float* __restrict__ zb, float* __restrict__ stat2)
{
    __shared__ float xnl[16 * 128];
    __shared__ float hidl[16 * 256];
    const int t  = threadIdx.x;
    const int n0 = blockIdx.x * 16;

    const float4* xg4 = (const float4*)(x + (size_t)n0 * 128);
    const float4* a4  = (const float4*)par;
    const float4* bv4 = (const float4*)(par + 128);
    float4* xnl4 = (float4*)xnl;
    #pragma unroll
    for (int i = 0; i < 4; ++i) {
        const int idx = i * 128 + t;
        const float4 xv = xg4[idx];
        const float4 av = a4[idx & 31], bv = bv4[idx & 31];
        float4 r;
        r.x = xv.x * av.x + bv.x; r.y = xv.y * av.y + bv.y;
        r.z = xv.z * av.z + bv.z; r.w = xv.w * av.w + bv.w;
        xnl4[idx] = r;
    }
    __syncthreads();

    // phase 1: hidden = relu(xn @ W1^T + b1)
    float acc0[16], acc1[16];
    #pragma unroll
    for (int n = 0; n < 16; ++n) { acc0[n] = 0.f; acc1[n] = 0.f; }
    const float* w0p = W1 + (size_t)t * 128;
    const float* w1p = W1 + (size_t)(t + 128) * 128;
    for (int kc = 0; kc < 32; ++kc) {
        const float4 w0 = *(const float4*)(w0p + kc * 4);
        const float4 w1 = *(const float4*)(w1p + kc * 4);
        #pragma unroll
        for (int n = 0; n < 16; ++n) {
            const float4 xv = *(const float4*)&xnl[n * 128 + kc * 4];
            acc0[n] += w0.x * xv.x + w0.y * xv.y + w0.z * xv.z + w0.w * xv.w;
            acc1[n] += w1.x * xv.x + w1.y * xv.y + w1.z * xv.z + w1.w * xv.w;
        }
    }
    const float bi0 = b1[t], bi1 = b1[t + 128];
    #pragma unroll
    for (int n = 0; n < 16; ++n) {
        hidl[n * 256 + t]       = fmaxf(acc0[n] + bi0, 0.f);
        hidl[n * 256 + 128 + t] = fmaxf(acc1[n] + bi1, 0.f);
    }
    __syncthreads();

    // phase 2: out = hidden @ W2^T + b2 ; z = xn + out
    float acc2[16];
    #pragma unroll
    for (int n = 0; n < 16; ++n) acc2[n] = 0.f;
    const float* w2p = W2 + (size_t)t * 256;
    for (int kc = 0; kc < 64; ++kc) {
        const float4 w = *(const float4*)(w2p + kc * 4);
        #pragma unroll
        for (int n = 0; n < 16; ++n) {
            const float4 hv = *(const float4*)&hidl[n * 256 + kc * 4];
            acc2[n] += w.x * hv.x + w.y * hv.y + w.z * hv.z + w.w * hv.w;
        }
    }
    const float bi2 = b2[t];
    float s = 0.f, sq = 0.f;
    float* zo = zb + (size_t)n0 * 128 + t;
    #pragma unroll
    for (int n = 0; n < 16; ++n) {
        const float z = xnl[n * 128 + t] + acc2[n] + bi2;
        zo[(size_t)n * 128] = z;
        s += z; sq += z * z;
    }
    atomicAdd(&stat2[t], s);
    atomicAdd(&stat2[128 + t], sq);
}

// ---------------------------------------------------------- final BN -------
__global__ void final_bn(const float4* __restrict__ zb, const float* __restrict__ pa,
                         const float* __restrict__ pb, float4* __restrict__ out, int total4)
{
    const float4* a4 = (const float4*)pa;
    const float4* b4 = (const float4*)pb;
    const int stride = gridDim.x * blockDim.x;
    for (int i = blockIdx.x * blockDim.x + threadIdx.x; i < total4; i += stride) {
        const float4 z = zb[i];
        const float4 a = a4[i & 31], b = b4[i & 31];
        float4 r;
        r.x = z.x * a.x + b.x; r.y = z.y * a.y + b.y;
        r.z = z.z * a.z + b.z; r.w = z.w * a.w + b.w;
        out[i] = r;
    }
}

// ---------------------------------------------------------------------------
extern "C" void kernel_launch(void* const* d_in, const int* in_sizes, int n_in,
                              void* d_out, int out_size, void* d_ws, size_t ws_size,
                              hipStream_t stream)
{
    const float* h   = (const float*)d_in[0];
    const int*   ei  = (const int*)  d_in[1];
    const float* ea  = (const float*)d_in[2];
    const float* Wq  = (const float*)d_in[3];
    const float* Wk  = (const float*)d_in[4];
    const float* Wv  = (const float*)d_in[5];
    const float* We  = (const float*)d_in[6];
    const float* Wb  = (const float*)d_in[7];
    const float* bbv = (const float*)d_in[8];
    const float* g1  = (const float*)d_in[9];
    const float* be1 = (const float*)d_in[10];
    const float* W1  = (const float*)d_in[11];
    const float* b1  = (const float*)d_in[12];
    const float* W2  = (const float*)d_in[13];
    const float* b2  = (const float*)d_in[14];
    const float* g2  = (const float*)d_in[15];
    const float* be2 = (const float*)d_in[16];
    float* out = (float*)d_out;

    const int N   = in_sizes[0] / 128;
    const int EDG = in_sizes[1] / 2;

    float* ws = (float*)d_ws;
    const size_t Q   = 0;
    const size_t K   = (size_t)N * 128;
    const size_t V   = 2 * (size_t)N * 128;
    const size_t WVB = 3 * (size_t)N * 128;      // wV; reused as z after resid_stats
    const size_t ZB  = 4 * (size_t)N * 128;
    const size_t XB  = ZB + (size_t)N * 8;
    const size_t ST  = XB + (size_t)N * 128;     // bn1 sum/sumsq, bn2 sum/sumsq (512 f)
    const size_t PAR = ST + 512;                 // a1,b1n,a2,b2n (512 f)

    // zero accumulators (wV + Z contiguous) and stats
    hipMemsetAsync(ws + WVB, 0, (size_t)N * 136 * sizeof(float), stream);
    hipMemsetAsync(ws + ST, 0, 512 * sizeof(float), stream);

    qkv_kernel<<<N / 16, 128, 0, stream>>>(h, Wq, Wk, Wv, ws + Q, ws + K, ws + V);
    edge_kernel<<<EDG / 128, 256, 0, stream>>>(ei, ea, We, Wb, bbv,
                                               ws + Q, ws + K, ws + V,
                                               ws + WVB, ws + ZB, EDG);
    resid_stats<<<512, 256, 0, stream>>>(h, ws + WVB, ws + ZB, ws + XB, ws + ST, N * 128);
    bn_params<<<1, 128, 0, stream>>>(ws + ST, ws + ST + 128, g1, be1,
                                     ws + PAR, ws + PAR + 128, 1.0f / (float)N);
    ffn_kernel<<<N / 16, 128, 0, stream>>>(ws + XB, W1, b1, W2, b2, ws + PAR,
                                           ws + WVB, ws + ST + 256);
    bn_params<<<1, 128, 0, stream>>>(ws + ST + 256, ws + ST + 384, g2, be2,
                                     ws + PAR + 256, ws + PAR + 384, 1.0f / (float)N);
    final_bn<<<1024, 256, 0, stream>>>((const float4*)(ws + WVB), ws + PAR + 256,
                                       ws + PAR + 384, (float4*)out, N * 32);
}

// Round 2
// 1645.837 us; speedup vs baseline: 3.8556x; 3.8556x over previous
//
#include <hip/hip_runtime.h>
#include <math.h>

typedef __attribute__((ext_vector_type(8))) short bf16x8;
typedef __attribute__((ext_vector_type(4))) short bf16x4;
typedef __attribute__((ext_vector_type(4))) float f32x4;

static __device__ __forceinline__ unsigned short f2bf(float x){
    union{float f; unsigned u;} v; v.f = x;
    unsigned r = v.u + 0x7fffu + ((v.u >> 16) & 1u);
    return (unsigned short)(r >> 16);
}
static __device__ __forceinline__ float bf2f(unsigned short b){
    union{unsigned u; float f;} v; v.u = ((unsigned)b) << 16; return v.f;
}

// ---------------------------------------------------------------- QKV ------
__global__ __launch_bounds__(128)
void qkv_kernel(const float* __restrict__ h,
                const float* __restrict__ Wq, const float* __restrict__ Wk,
                const float* __restrict__ Wv,
                float* __restrict__ Qb, float* __restrict__ Kb, float* __restrict__ Vb)
{
    __shared__ float hl[16 * 128];
    const int t  = threadIdx.x;
    const int n0 = blockIdx.x * 16;

    const float4* hg4 = (const float4*)(h + (size_t)n0 * 128);
    float4* hl4 = (float4*)hl;
    #pragma unroll
    for (int i = 0; i < 4; ++i) hl4[i * 128 + t] = hg4[i * 128 + t];
    __syncthreads();

    #pragma unroll
    for (int m = 0; m < 3; ++m) {
        const float* W = (m == 0 ? Wq : (m == 1 ? Wk : Wv)) + t * 128;
        float*       o = (m == 0 ? Qb : (m == 1 ? Kb : Vb)) + (size_t)n0 * 128 + t;
        float acc[16];
        #pragma unroll
        for (int n = 0; n < 16; ++n) acc[n] = 0.f;
        for (int kc = 0; kc < 32; ++kc) {
            const float4 w = *(const float4*)(W + kc * 4);
            #pragma unroll
            for (int n = 0; n < 16; ++n) {
                const float4 x = *(const float4*)&hl[n * 128 + kc * 4];
                acc[n] += w.x * x.x + w.y * x.y + w.z * x.z + w.w * x.w;
            }
        }
        #pragma unroll
        for (int n = 0; n < 16; ++n) o[(size_t)n * 128] = acc[n];
    }
}

// ------------------------------------------------------------- CSR build ---
__global__ void hist_kernel(const int* __restrict__ ei, int* __restrict__ cnt, int EDG)
{
    const int stride = gridDim.x * blockDim.x;
    for (int e = blockIdx.x * blockDim.x + threadIdx.x; e < EDG; e += stride)
        atomicAdd(&cnt[ei[EDG + e]], 1);
}

__global__ __launch_bounds__(1024)
void scan_kernel(const int* __restrict__ cnt, int* __restrict__ offs, int n)
{
    __shared__ int tmp[1024];
    __shared__ int carry;
    const int t = threadIdx.x;
    if (t == 0) carry = 0;
    __syncthreads();
    for (int base = 0; base < n; base += 1024) {
        int v = (base + t < n) ? cnt[base + t] : 0;
        tmp[t] = v;
        __syncthreads();
        for (int d = 1; d < 1024; d <<= 1) {
            int a = (t >= d) ? tmp[t - d] : 0;
            __syncthreads();
            tmp[t] += a;
            __syncthreads();
        }
        if (base + t < n) offs[base + t] = carry + tmp[t] - v;  // exclusive
        __syncthreads();
        if (t == 1023) carry += tmp[1023];
        __syncthreads();
    }
    if (t == 0) offs[n] = carry;
}

__global__ void scatter_kernel(const int* __restrict__ ei, const int* __restrict__ offs,
                               int* __restrict__ cur, int2* __restrict__ elist, int EDG)
{
    const int stride = gridDim.x * blockDim.x;
    for (int e = blockIdx.x * blockDim.x + threadIdx.x; e < EDG; e += stride) {
        const int d = ei[EDG + e];
        const int p = atomicAdd(&cur[d], 1);
        int2 v; v.x = ei[e]; v.y = e;
        elist[offs[d] + p] = v;
    }
}

// ----------------------------------------------------- edge scores (MFMA) --
// Per block: stage WeB/WbB (bf16, XOR-swizzled) once; 4 iters x 64 edges.
// Wave w computes 16 edges: per head tile M=16 dims, N=16 edges, K=128.
// D layout: col=lane&15 (edge), row=(lane>>4)*4+reg (dim within head).
__global__ __launch_bounds__(256, 2)
void edge_score(const int* __restrict__ ei, const float* __restrict__ eattr,
                const float* __restrict__ We, const float* __restrict__ Wb,
                const float* __restrict__ bbv,
                const float* __restrict__ Qb, const float* __restrict__ Kb,
                float* __restrict__ scoreP, int EDG)
{
    __shared__ unsigned short WeB[128 * 128];  // (d,k): byte d*256 + ((2k)^((d&7)<<4))
    __shared__ unsigned short WbB[16 * 128];   // rows 8..15 zero
    __shared__ unsigned short eaB[64 * 128];   // (e,k): byte e*256 + ((2k)^((e&7)<<4))
    __shared__ unsigned short Gb[64 * 136];    // (e,d): byte e*272 + 2d  (K[src]*Q[dst], bf16)
    const int t = threadIdx.x;

    // ---- stage WeB ----
    #pragma unroll
    for (int i = 0; i < 16; ++i) {
        const int idx4 = i * 256 + t;              // 0..4095
        const int d = idx4 >> 5, k0 = (idx4 & 31) * 4;
        const float4 w = *(const float4*)&We[d * 128 + k0];
        bf16x4 p;
        p[0] = (short)f2bf(w.x); p[1] = (short)f2bf(w.y);
        p[2] = (short)f2bf(w.z); p[3] = (short)f2bf(w.w);
        *(bf16x4*)((char*)WeB + d * 256 + ((2 * k0) ^ ((d & 7) << 4))) = p;
    }
    // ---- stage WbB ----
    #pragma unroll
    for (int i = 0; i < 8; ++i) {
        const int idx = i * 256 + t;               // 0..2047
        const int r = idx >> 7, k = idx & 127;
        const unsigned short v = (r < 8) ? f2bf(Wb[r * 128 + k]) : (unsigned short)0;
        *(unsigned short*)((char*)WbB + r * 256 + ((2 * k) ^ ((r & 7) << 4))) = v;
    }

    const int l = t & 63, w = t >> 6;
    const int le = t >> 2, lj = t & 3;             // G staging: 64 edges x 4 threads

    for (int it = 0; it < 4; ++it) {
        __syncthreads();
        const int e0 = (blockIdx.x * 4 + it) * 64;

        // ---- stage eaB (fp32 -> bf16, swizzled) ----
        #pragma unroll
        for (int i = 0; i < 4; ++i) {
            const int idx4 = i * 256 + t;          // 0..1023
            const int e = idx4 >> 4, k0 = (idx4 & 15) * 8;
            if (e0 + e < EDG) {
                const float4 a0 = *(const float4*)&eattr[(size_t)(e0 + e) * 128 + k0];
                const float4 a1 = *(const float4*)&eattr[(size_t)(e0 + e) * 128 + k0 + 4];
                bf16x8 p;
                p[0] = (short)f2bf(a0.x); p[1] = (short)f2bf(a0.y);
                p[2] = (short)f2bf(a0.z); p[3] = (short)f2bf(a0.w);
                p[4] = (short)f2bf(a1.x); p[5] = (short)f2bf(a1.y);
                p[6] = (short)f2bf(a1.z); p[7] = (short)f2bf(a1.w);
                *(bf16x8*)((char*)eaB + e * 256 + ((2 * k0) ^ ((e & 7) << 4))) = p;
            }
        }
        // ---- stage Gb = bf16(K[src]*Q[dst]) ----
        {
            const int ge = e0 + le;
            if (ge < EDG) {
                const int s = ei[ge], d = ei[EDG + ge];
                const float* kr = &Kb[(size_t)s * 128];
                const float* qr = &Qb[(size_t)d * 128];
                #pragma unroll
                for (int i = 0; i < 8; ++i) {
                    const int dd = lj * 32 + i * 4;
                    const float4 kk = *(const float4*)&kr[dd];
                    const float4 qq = *(const float4*)&qr[dd];
                    bf16x4 p;
                    p[0] = (short)f2bf(kk.x * qq.x); p[1] = (short)f2bf(kk.y * qq.y);
                    p[2] = (short)f2bf(kk.z * qq.z); p[3] = (short)f2bf(kk.w * qq.w);
                    *(bf16x4*)((char*)Gb + le * 272 + dd * 2) = p;
                }
            }
        }
        __syncthreads();

        // ---- MFMA: 8 head tiles + 1 bias tile, K=128 ----
        f32x4 acc[8], accb;
        #pragma unroll
        for (int h = 0; h < 8; ++h) acc[h] = (f32x4){0.f, 0.f, 0.f, 0.f};
        accb = (f32x4){0.f, 0.f, 0.f, 0.f};

        const int kb_l = (l >> 4) * 16;            // per-lane k byte sub-offset
        const int erow = w * 16 + (l & 15);
        const int brow = l & 15;
        #pragma unroll
        for (int ks = 0; ks < 4; ++ks) {
            const int kb = ks * 64 + kb_l;
            const bf16x8 bfr = *(const bf16x8*)((char*)eaB + erow * 256 + (kb ^ ((erow & 7) << 4)));
            const bf16x8 abf = *(const bf16x8*)((char*)WbB + brow * 256 + (kb ^ ((brow & 7) << 4)));
            accb = __builtin_amdgcn_mfma_f32_16x16x32_bf16(abf, bfr, accb, 0, 0, 0);
            #pragma unroll
            for (int h = 0; h < 8; ++h) {
                const int ar = h * 16 + (l & 15);
                const bf16x8 af = *(const bf16x8*)((char*)WeB + ar * 256 + (kb ^ ((ar & 7) << 4)));
                acc[h] = __builtin_amdgcn_mfma_f32_16x16x32_bf16(af, bfr, acc[h], 0, 0, 0);
            }
        }

        // ---- score: per-lane dot over 4 dims, reduce over lane-groups ----
        const int eloc = l & 15;
        const int ge = e0 + w * 16 + eloc;
        #pragma unroll
        for (int h = 0; h < 8; ++h) {
            const bf16x4 g4 = *(const bf16x4*)((char*)Gb + (w * 16 + eloc) * 272 +
                                               (h * 16 + (l >> 4) * 4) * 2);
            float m = acc[h][0] * bf2f((unsigned short)g4[0])
                    + acc[h][1] * bf2f((unsigned short)g4[1])
                    + acc[h][2] * bf2f((unsigned short)g4[2])
                    + acc[h][3] * bf2f((unsigned short)g4[3]);
            m += __shfl_xor(m, 16);
            m += __shfl_xor(m, 32);
            const float eb = __shfl(accb[h & 3], ((h >> 2) << 4) | eloc);
            float s = m * 0.25f + eb + bbv[h];
            s = expf(fminf(fmaxf(s, -5.f), 5.f));
            if (l < 16 && ge < EDG) scoreP[(size_t)ge * 8 + h] = s;
        }
    }
}

// ------------------------------------------------- gather + resid + stats --
__global__ __launch_bounds__(256)
void gather_kernel(const int2* __restrict__ elist, const int* __restrict__ offs,
                   const float* __restrict__ score, const float* __restrict__ Vb,
                   const float* __restrict__ h, float* __restrict__ x,
                   float* __restrict__ stat, int N)
{
    __shared__ float ssl[4][128], sql[4][128];
    const int t = threadIdx.x, w = t >> 6, l = t & 63;
    const int node = blockIdx.x * 4 + w;
    const int hh = l >> 3;

    if (node < N) {
        float2 acc = {0.f, 0.f};
        float z = 0.f;
        const int beg = offs[node], end = offs[node + 1];
        for (int i = beg; i < end; ++i) {
            const int2 se = elist[i];
            const float sc = score[(size_t)se.y * 8 + hh];
            const float2 v = *(const float2*)&Vb[(size_t)se.x * 128 + 2 * l];
            acc.x += v.x * sc; acc.y += v.y * sc; z += sc;
        }
        const float inv = 1.f / (z + 1e-6f);
        const float2 hv = *(const float2*)&h[(size_t)node * 128 + 2 * l];
        float2 xv; xv.x = hv.x + acc.x * inv; xv.y = hv.y + acc.y * inv;
        *(float2*)&x[(size_t)node * 128 + 2 * l] = xv;
        ssl[w][2 * l] = xv.x; ssl[w][2 * l + 1] = xv.y;
        sql[w][2 * l] = xv.x * xv.x; sql[w][2 * l + 1] = xv.y * xv.y;
    } else {
        ssl[w][2 * l] = 0.f; ssl[w][2 * l + 1] = 0.f;
        sql[w][2 * l] = 0.f; sql[w][2 * l + 1] = 0.f;
    }
    __syncthreads();
    if (t < 128) {
        const float s = ssl[0][t] + ssl[1][t] + ssl[2][t] + ssl[3][t];
        const float q = sql[0][t] + sql[1][t] + sql[2][t] + sql[3][t];
        atomicAdd(&stat[t], s);
        atomicAdd(&stat[128 + t], q);
    }
}

// ---------------------------------------------------------- BN params ------
__global__ void bn_params(const float* __restrict__ sum, const float* __restrict__ sumsq,
                          const float* __restrict__ gamma, const float* __restrict__ beta,
                          float* __restrict__ a, float* __restrict__ b, float invn)
{
    const int c = threadIdx.x;
    const float mean = sum[c] * invn;
    const float var  = sumsq[c] * invn - mean * mean;
    const float sc   = gamma[c] * rsqrtf(var + 1e-5f);
    a[c] = sc;
    b[c] = beta[c] - mean * sc;
}

// ---------------------------------------------------------------- FFN ------
__global__ __launch_bounds__(128)
void ffn_kernel(const float* __restrict__ x, const float* __restrict__ W1,
                const float* __restrict__ b1, const float* __restrict__ W2,
                const float* __restrict__ b2, const float* __restrict__ par,
                float* __restrict__ zb, float* __restrict__ stat2)
{
    __shared__ float xnl[16 * 128];
    __shared__ float hidl[16 * 256];
    const int t  = threadIdx.x;
    const int n0 = blockIdx.x * 16;

    const float4* xg4 = (const float4*)(x + (size_t)n0 * 128);
    const float4* a4  = (const float4*)par;
    const float4* bv4 = (const float4*)(par + 128);
    float4* xnl4 = (float4*)xnl;
    #pragma unroll
    for (int i = 0; i < 4; ++i) {
        const int idx = i * 128 + t;
        const float4 xv = xg4[idx];
        const float4 av = a4[idx & 31], bv = bv4[idx & 31];
        float4 r;
        r.x = xv.x * av.x + bv.x; r.y = xv.y * av.y + bv.y;
        r.z = xv.z * av.z + bv.z; r.w = xv.w * av.w + bv.w;
        xnl4[idx] = r;
    }
    __syncthreads();

    float acc0[16], acc1[16];
    #pragma unroll
    for (int n = 0; n < 16; ++n) { acc0[n] = 0.f; acc1[n] = 0.f; }
    const float* w0p = W1 + (size_t)t * 128;
    const float* w1p = W1 + (size_t)(t + 128) * 128;
    for (int kc = 0; kc < 32; ++kc) {
        const float4 w0 = *(const float4*)(w0p + kc * 4);
        const float4 w1 = *(const float4*)(w1p + kc * 4);
        #pragma unroll
        for (int n = 0; n < 16; ++n) {
            const float4 xv = *(const float4*)&xnl[n * 128 + kc * 4];
            acc0[n] += w0.x * xv.x + w0.y * xv.y + w0.z * xv.z + w0.w * xv.w;
            acc1[n] += w1.x * xv.x + w1.y * xv.y + w1.z * xv.z + w1.w * xv.w;
        }
    }
    const float bi0 = b1[t], bi1 = b1[t + 128];
    #pragma unroll
    for (int n = 0; n < 16; ++n) {
        hidl[n * 256 + t]       = fmaxf(acc0[n] + bi0, 0.f);
        hidl[n * 256 + 128 + t] = fmaxf(acc1[n] + bi1, 0.f);
    }
    __syncthreads();

    float acc2[16];
    #pragma unroll
    for (int n = 0; n < 16; ++n) acc2[n] = 0.f;
    const float* w2p = W2 + (size_t)t * 256;
    for (int kc = 0; kc < 64; ++kc) {
        const float4 w = *(const float4*)(w2p + kc * 4);
        #pragma unroll
        for (int n = 0; n < 16; ++n) {
            const float4 hv = *(const float4*)&hidl[n * 256 + kc * 4];
            acc2[n] += w.x * hv.x + w.y * hv.y + w.z * hv.z + w.w * hv.w;
        }
    }
    const float bi2 = b2[t];
    float s = 0.f, sq = 0.f;
    float* zo = zb + (size_t)n0 * 128 + t;
    #pragma unroll
    for (int n = 0; n < 16; ++n) {
        const float z = xnl[n * 128 + t] + acc2[n] + bi2;
        zo[(size_t)n * 128] = z;
        s += z; sq += z * z;
    }
    atomicAdd(&stat2[t], s);
    atomicAdd(&stat2[128 + t], sq);
}

// ---------------------------------------------------------- final BN -------
__global__ void final_bn(const float4* __restrict__ zb, const float* __restrict__ pa,
                         const float* __restrict__ pb, float4* __restrict__ out, int total4)
{
    const float4* a4 = (const float4*)pa;
    const float4* b4 = (const float4*)pb;
    const int stride = gridDim.x * blockDim.x;
    for (int i = blockIdx.x * blockDim.x + threadIdx.x; i < total4; i += stride) {
        const float4 z = zb[i];
        const float4 a = a4[i & 31], b = b4[i & 31];
        float4 r;
        r.x = z.x * a.x + b.x; r.y = z.y * a.y + b.y;
        r.z = z.z * a.z + b.z; r.w = z.w * a.w + b.w;
        out[i] = r;
    }
}

// ---------------------------------------------------------------------------
extern "C" void kernel_launch(void* const* d_in, const int* in_sizes, int n_in,
                              void* d_out, int out_size, void* d_ws, size_t ws_size,
                              hipStream_t stream)
{
    const float* h   = (const float*)d_in[0];
    const int*   ei  = (const int*)  d_in[1];
    const float* ea  = (const float*)d_in[2];
    const float* Wq  = (const float*)d_in[3];
    const float* Wk  = (const float*)d_in[4];
    const float* Wv  = (const float*)d_in[5];
    const float* We  = (const float*)d_in[6];
    const float* Wb  = (const float*)d_in[7];
    const float* bbv = (const float*)d_in[8];
    const float* g1  = (const float*)d_in[9];
    const float* be1 = (const float*)d_in[10];
    const float* W1  = (const float*)d_in[11];
    const float* b1  = (const float*)d_in[12];
    const float* W2  = (const float*)d_in[13];
    const float* b2  = (const float*)d_in[14];
    const float* g2  = (const float*)d_in[15];
    const float* be2 = (const float*)d_in[16];
    float* out = (float*)d_out;

    const int N   = in_sizes[0] / 128;
    const int EDG = in_sizes[1] / 2;
    const size_t nd = (size_t)N * 128;

    float* ws = (float*)d_ws;
    const size_t Qo  = 0;                       // Qb; reused as x after edge_score
    const size_t Ko  = nd;                      // Kb; reused as z after ffn input ready
    const size_t Vo  = 2 * nd;                  // Vb
    const size_t SCo = 3 * nd;                  // score (EDG*8 f32)
    const size_t ELo = SCo + (size_t)EDG * 8;   // elist (EDG int2) — 8B aligned
    const size_t OFo = ELo + (size_t)EDG * 2;   // offs (N+1 ints)
    const size_t CUo = OFo + (size_t)(N + 2);   // cursor/counts (N ints)
    const size_t STo = CUo + (size_t)N;         // stats: 512 f32
    const size_t PAR = STo + 512;               // bn params: 512 f32

    int*  cnt   = (int*)(ws + CUo);
    int*  offs  = (int*)(ws + OFo);
    int2* elist = (int2*)(ws + ELo);

    hipMemsetAsync(cnt, 0, (size_t)N * sizeof(int), stream);
    hipMemsetAsync(ws + STo, 0, 512 * sizeof(float), stream);

    qkv_kernel<<<N / 16, 128, 0, stream>>>(h, Wq, Wk, Wv, ws + Qo, ws + Ko, ws + Vo);

    hist_kernel<<<1024, 256, 0, stream>>>(ei, cnt, EDG);
    scan_kernel<<<1, 1024, 0, stream>>>(cnt, offs, N);
    hipMemsetAsync(cnt, 0, (size_t)N * sizeof(int), stream);
    scatter_kernel<<<1024, 256, 0, stream>>>(ei, offs, cnt, elist, EDG);

    edge_score<<<(EDG + 255) / 256, 256, 0, stream>>>(ei, ea, We, Wb, bbv,
                                                      ws + Qo, ws + Ko,
                                                      ws + SCo, EDG);

    gather_kernel<<<(N + 3) / 4, 256, 0, stream>>>(elist, offs, ws + SCo, ws + Vo,
                                                   h, ws + Qo, ws + STo, N);

    bn_params<<<1, 128, 0, stream>>>(ws + STo, ws + STo + 128, g1, be1,
                                     ws + PAR, ws + PAR + 128, 1.0f / (float)N);
    ffn_kernel<<<N / 16, 128, 0, stream>>>(ws + Qo, W1, b1, W2, b2, ws + PAR,
                                           ws + Ko, ws + STo + 256);
    bn_params<<<1, 128, 0, stream>>>(ws + STo + 256, ws + STo + 384, g2, be2,
                                     ws + PAR + 256, ws + PAR + 384, 1.0f / (float)N);
    final_bn<<<1024, 256, 0, stream>>>((const float4*)(ws + Ko), ws + PAR + 256,
                                       ws + PAR + 384, (float4*)out, N * 32);
}

// Round 3
// 1409.659 us; speedup vs baseline: 4.5016x; 1.1675x over previous
//
#include <hip/hip_runtime.h>
#include <math.h>

typedef __attribute__((ext_vector_type(8))) short bf16x8;
typedef __attribute__((ext_vector_type(4))) short bf16x4;
typedef __attribute__((ext_vector_type(4))) float f32x4;

static __device__ __forceinline__ unsigned short f2bf(float x){
    union{float f; unsigned u;} v; v.f = x;
    unsigned r = v.u + 0x7fffu + ((v.u >> 16) & 1u);
    return (unsigned short)(r >> 16);
}

// ---------------------------------------------------------------- QKV ------
__global__ __launch_bounds__(128)
void qkv_kernel(const float* __restrict__ h,
                const float* __restrict__ Wq, const float* __restrict__ Wk,
                const float* __restrict__ Wv,
                float* __restrict__ Qb, float* __restrict__ Kb, float* __restrict__ Vb)
{
    __shared__ float hl[16 * 128];
    const int t  = threadIdx.x;
    const int n0 = blockIdx.x * 16;

    const float4* hg4 = (const float4*)(h + (size_t)n0 * 128);
    float4* hl4 = (float4*)hl;
    #pragma unroll
    for (int i = 0; i < 4; ++i) hl4[i * 128 + t] = hg4[i * 128 + t];
    __syncthreads();

    #pragma unroll
    for (int m = 0; m < 3; ++m) {
        const float* W = (m == 0 ? Wq : (m == 1 ? Wk : Wv)) + t * 128;
        float*       o = (m == 0 ? Qb : (m == 1 ? Kb : Vb)) + (size_t)n0 * 128 + t;
        float acc[16];
        #pragma unroll
        for (int n = 0; n < 16; ++n) acc[n] = 0.f;
        for (int kc = 0; kc < 32; ++kc) {
            const float4 w = *(const float4*)(W + kc * 4);
            #pragma unroll
            for (int n = 0; n < 16; ++n) {
                const float4 x = *(const float4*)&hl[n * 128 + kc * 4];
                acc[n] += w.x * x.x + w.y * x.y + w.z * x.z + w.w * x.w;
            }
        }
        #pragma unroll
        for (int n = 0; n < 16; ++n) o[(size_t)n * 128] = acc[n];
    }
}

// ------------------------------------------------------------- CSR build ---
__global__ void hist_kernel(const int* __restrict__ ei, int* __restrict__ cnt, int EDG)
{
    const int stride = gridDim.x * blockDim.x;
    for (int e = blockIdx.x * blockDim.x + threadIdx.x; e < EDG; e += stride)
        atomicAdd(&cnt[ei[EDG + e]], 1);
}

// block-level sums
__global__ __launch_bounds__(1024)
void scan_a(const int* __restrict__ cnt, int* __restrict__ bsum, int n)
{
    __shared__ int tmp[1024];
    const int t = threadIdx.x;
    const int i = blockIdx.x * 1024 + t;
    tmp[t] = (i < n) ? cnt[i] : 0;
    __syncthreads();
    for (int d = 512; d > 0; d >>= 1) {
        if (t < d) tmp[t] += tmp[t + d];
        __syncthreads();
    }
    if (t == 0) bsum[blockIdx.x] = tmp[0];
}

// tiny serial scan of block sums (nb ~ 49)
__global__ void scan_b(const int* __restrict__ bsum, int* __restrict__ bbase,
                       int* __restrict__ offs, int nb, int n)
{
    if (threadIdx.x == 0) {
        int run = 0;
        for (int b = 0; b < nb; ++b) { bbase[b] = run; run += bsum[b]; }
        offs[n] = run;
    }
}

// per-block exclusive scan + base
__global__ __launch_bounds__(1024)
void scan_c(const int* __restrict__ cnt, const int* __restrict__ bbase,
            int* __restrict__ offs, int n)
{
    __shared__ int tmp[1024];
    const int t = threadIdx.x;
    const int i = blockIdx.x * 1024 + t;
    const int v = (i < n) ? cnt[i] : 0;
    tmp[t] = v;
    __syncthreads();
    for (int d = 1; d < 1024; d <<= 1) {
        const int a = (t >= d) ? tmp[t - d] : 0;
        __syncthreads();
        tmp[t] += a;
        __syncthreads();
    }
    if (i < n) offs[i] = bbase[blockIdx.x] + tmp[t] - v;
}

__global__ void scatter_kernel(const int* __restrict__ ei, const int* __restrict__ offs,
                               int* __restrict__ cur, int2* __restrict__ elist, int EDG)
{
    const int stride = gridDim.x * blockDim.x;
    for (int e = blockIdx.x * blockDim.x + threadIdx.x; e < EDG; e += stride) {
        const int d = ei[EDG + e];
        const int p = atomicAdd(&cur[d], 1);
        int2 v; v.x = ei[e]; v.y = e;
        elist[offs[d] + p] = v;
    }
}

// ----------------------------------------------------- edge scores (MFMA) --
// 4 waves x 16 edges, tile = 64 edges, 4 tiles/block. We/Wb in LDS (bf16,
// XOR-swizzled); eattr reg-prefetched (T14) then staged; K/Q gathered
// per-lane in fp32 and dotted against the MFMA accumulator (no G tile).
__global__ __launch_bounds__(256, 3)
void edge_score(const int* __restrict__ ei, const float* __restrict__ eattr,
                const float* __restrict__ We, const float* __restrict__ Wb,
                const float* __restrict__ bbv,
                const float* __restrict__ Qb, const float* __restrict__ Kb,
                float* __restrict__ scoreP, int EDG)
{
    __shared__ unsigned short WeB[128 * 128];  // 32 KB (d,k): byte d*256 + ((2k)^((d&7)<<4))
    __shared__ unsigned short WbB[16 * 128];   // 4 KB, rows 8..15 zero
    __shared__ unsigned short eaB[64 * 128];   // 16 KB (e,k): byte e*256 + ((2k)^((e&7)<<4))
    const int t = threadIdx.x;

    // ---- stage WeB ----
    #pragma unroll
    for (int i = 0; i < 16; ++i) {
        const int idx4 = i * 256 + t;              // 0..4095
        const int d = idx4 >> 5, k0 = (idx4 & 31) * 4;
        const float4 w = *(const float4*)&We[d * 128 + k0];
        bf16x4 p;
        p[0] = (short)f2bf(w.x); p[1] = (short)f2bf(w.y);
        p[2] = (short)f2bf(w.z); p[3] = (short)f2bf(w.w);
        *(bf16x4*)((char*)WeB + d * 256 + ((2 * k0) ^ ((d & 7) << 4))) = p;
    }
    // ---- stage WbB ----
    #pragma unroll
    for (int i = 0; i < 8; ++i) {
        const int idx = i * 256 + t;               // 0..2047
        const int r = idx >> 7, k = idx & 127;
        const unsigned short v = (r < 8) ? f2bf(Wb[r * 128 + k]) : (unsigned short)0;
        *(unsigned short*)((char*)WbB + r * 256 + ((2 * k) ^ ((r & 7) << 4))) = v;
    }

    const int l = t & 63, w = t >> 6;
    const int eloc = l & 15;
    const int g4 = l >> 4;                         // 0..3 k/dim sub-group
    const int base0 = blockIdx.x * 256;

    // ---- prefetch tile 0 eattr into registers ----
    float4 pa[4][2];
    #pragma unroll
    for (int i = 0; i < 4; ++i) {
        const int idx4 = i * 256 + t;              // 0..1023
        const int e = idx4 >> 4, k0 = (idx4 & 15) * 8;
        if (base0 + e < EDG) {
            const size_t off = (size_t)(base0 + e) * 128 + k0;
            pa[i][0] = *(const float4*)&eattr[off];
            pa[i][1] = *(const float4*)&eattr[off + 4];
        }
    }

    for (int it = 0; it < 4; ++it) {
        const int e0 = base0 + it * 64;
        __syncthreads();                            // eaB consumers of prev tile done

        // ---- write prefetched regs -> eaB (bf16, swizzled) ----
        #pragma unroll
        for (int i = 0; i < 4; ++i) {
            const int idx4 = i * 256 + t;
            const int e = idx4 >> 4, k0 = (idx4 & 15) * 8;
            bf16x8 p;
            p[0] = (short)f2bf(pa[i][0].x); p[1] = (short)f2bf(pa[i][0].y);
            p[2] = (short)f2bf(pa[i][0].z); p[3] = (short)f2bf(pa[i][0].w);
            p[4] = (short)f2bf(pa[i][1].x); p[5] = (short)f2bf(pa[i][1].y);
            p[6] = (short)f2bf(pa[i][1].z); p[7] = (short)f2bf(pa[i][1].w);
            *(bf16x8*)((char*)eaB + e * 256 + ((2 * k0) ^ ((e & 7) << 4))) = p;
        }
        // ---- issue next tile's eattr loads (land during compute) ----
        if (it < 3) {
            const int eb0 = e0 + 64;
            #pragma unroll
            for (int i = 0; i < 4; ++i) {
                const int idx4 = i * 256 + t;
                const int e = idx4 >> 4, k0 = (idx4 & 15) * 8;
                if (eb0 + e < EDG) {
                    const size_t off = (size_t)(eb0 + e) * 128 + k0;
                    pa[i][0] = *(const float4*)&eattr[off];
                    pa[i][1] = *(const float4*)&eattr[off + 4];
                }
            }
        }
        __syncthreads();

        // per-lane edge + src/dst (issues before MFMAs; gathers overlap them)
        const int ge  = e0 + w * 16 + eloc;
        const int gec = (ge < EDG) ? ge : (EDG > 0 ? EDG - 1 : 0);
        const int s  = ei[gec];
        const int d  = ei[EDG + gec];
        const float* kr = &Kb[(size_t)s * 128 + g4 * 4];
        const float* qr = &Qb[(size_t)d * 128 + g4 * 4];

        // ---- MFMA: 8 head tiles + 1 bias tile, K=128 ----
        f32x4 acc[8], accb;
        #pragma unroll
        for (int h = 0; h < 8; ++h) acc[h] = (f32x4){0.f, 0.f, 0.f, 0.f};
        accb = (f32x4){0.f, 0.f, 0.f, 0.f};

        const int kb_l = g4 * 16;
        const int erow = w * 16 + eloc;
        const int brow = eloc;
        #pragma unroll
        for (int ks = 0; ks < 4; ++ks) {
            const int kb = ks * 64 + kb_l;
            const bf16x8 bfr = *(const bf16x8*)((char*)eaB + erow * 256 + (kb ^ ((erow & 7) << 4)));
            const bf16x8 abf = *(const bf16x8*)((char*)WbB + brow * 256 + (kb ^ ((brow & 7) << 4)));
            accb = __builtin_amdgcn_mfma_f32_16x16x32_bf16(abf, bfr, accb, 0, 0, 0);
            #pragma unroll
            for (int h = 0; h < 8; ++h) {
                const int ar = h * 16 + eloc;
                const bf16x8 af = *(const bf16x8*)((char*)WeB + ar * 256 + (kb ^ ((ar & 7) << 4)));
                acc[h] = __builtin_amdgcn_mfma_f32_16x16x32_bf16(af, bfr, acc[h], 0, 0, 0);
            }
        }

        // ---- epilogue: per-lane fp32 K*Q dot vs acc, cross-lane reduce ----
        #pragma unroll
        for (int h = 0; h < 8; ++h) {
            const float4 kk = *(const float4*)(kr + h * 16);
            const float4 qq = *(const float4*)(qr + h * 16);
            float m = acc[h][0] * (kk.x * qq.x) + acc[h][1] * (kk.y * qq.y)
                    + acc[h][2] * (kk.z * qq.z) + acc[h][3] * (kk.w * qq.w);
            m += __shfl_xor(m, 16);
            m += __shfl_xor(m, 32);
            const float eb = __shfl(accb[h & 3], ((h >> 2) << 4) | eloc);
            float sc = m * 0.25f + eb + bbv[h];
            sc = expf(fminf(fmaxf(sc, -5.f), 5.f));
            if (l < 16 && ge < EDG) scoreP[(size_t)ge * 8 + h] = sc;
        }
    }
}

// ------------------------------------------------- gather + resid + stats --
__global__ __launch_bounds__(256)
void gather_kernel(const int2* __restrict__ elist, const int* __restrict__ offs,
                   const float* __restrict__ score, const float* __restrict__ Vb,
                   const float* __restrict__ h, float* __restrict__ x,
                   float* __restrict__ stat, int N)
{
    __shared__ float ssl[4][128], sql[4][128];
    const int t = threadIdx.x, w = t >> 6, l = t & 63;
    const int node = blockIdx.x * 4 + w;
    const int hh = l >> 3;

    if (node < N) {
        float2 acc = {0.f, 0.f};
        float z = 0.f;
        const int beg = offs[node], end = offs[node + 1];
        for (int i = beg; i < end; ++i) {
            const int2 se = elist[i];
            const float sc = score[(size_t)se.y * 8 + hh];
            const float2 v = *(const float2*)&Vb[(size_t)se.x * 128 + 2 * l];
            acc.x += v.x * sc; acc.y += v.y * sc; z += sc;
        }
        const float inv = 1.f / (z + 1e-6f);
        const float2 hv = *(const float2*)&h[(size_t)node * 128 + 2 * l];
        float2 xv; xv.x = hv.x + acc.x * inv; xv.y = hv.y + acc.y * inv;
        *(float2*)&x[(size_t)node * 128 + 2 * l] = xv;
        ssl[w][2 * l] = xv.x; ssl[w][2 * l + 1] = xv.y;
        sql[w][2 * l] = xv.x * xv.x; sql[w][2 * l + 1] = xv.y * xv.y;
    } else {
        ssl[w][2 * l] = 0.f; ssl[w][2 * l + 1] = 0.f;
        sql[w][2 * l] = 0.f; sql[w][2 * l + 1] = 0.f;
    }
    __syncthreads();
    if (t < 128) {
        const float s = ssl[0][t] + ssl[1][t] + ssl[2][t] + ssl[3][t];
        const float q = sql[0][t] + sql[1][t] + sql[2][t] + sql[3][t];
        atomicAdd(&stat[t], s);
        atomicAdd(&stat[128 + t], q);
    }
}

// ---------------------------------------------------------- BN params ------
__global__ void bn_params(const float* __restrict__ sum, const float* __restrict__ sumsq,
                          const float* __restrict__ gamma, const float* __restrict__ beta,
                          float* __restrict__ a, float* __restrict__ b, float invn)
{
    const int c = threadIdx.x;
    const float mean = sum[c] * invn;
    const float var  = sumsq[c] * invn - mean * mean;
    const float sc   = gamma[c] * rsqrtf(var + 1e-5f);
    a[c] = sc;
    b[c] = beta[c] - mean * sc;
}

// ---------------------------------------------------------------- FFN ------
__global__ __launch_bounds__(128)
void ffn_kernel(const float* __restrict__ x, const float* __restrict__ W1,
                const float* __restrict__ b1, const float* __restrict__ W2,
                const float* __restrict__ b2, const float* __restrict__ par,
                float* __restrict__ zb, float* __restrict__ stat2)
{
    __shared__ float xnl[16 * 128];
    __shared__ float hidl[16 * 256];
    const int t  = threadIdx.x;
    const int n0 = blockIdx.x * 16;

    const float4* xg4 = (const float4*)(x + (size_t)n0 * 128);
    const float4* a4  = (const float4*)par;
    const float4* bv4 = (const float4*)(par + 128);
    float4* xnl4 = (float4*)xnl;
    #pragma unroll
    for (int i = 0; i < 4; ++i) {
        const int idx = i * 128 + t;
        const float4 xv = xg4[idx];
        const float4 av = a4[idx & 31], bv = bv4[idx & 31];
        float4 r;
        r.x = xv.x * av.x + bv.x; r.y = xv.y * av.y + bv.y;
        r.z = xv.z * av.z + bv.z; r.w = xv.w * av.w + bv.w;
        xnl4[idx] = r;
    }
    __syncthreads();

    float acc0[16], acc1[16];
    #pragma unroll
    for (int n = 0; n < 16; ++n) { acc0[n] = 0.f; acc1[n] = 0.f; }
    const float* w0p = W1 + (size_t)t * 128;
    const float* w1p = W1 + (size_t)(t + 128) * 128;
    for (int kc = 0; kc < 32; ++kc) {
        const float4 w0 = *(const float4*)(w0p + kc * 4);
        const float4 w1 = *(const float4*)(w1p + kc * 4);
        #pragma unroll
        for (int n = 0; n < 16; ++n) {
            const float4 xv = *(const float4*)&xnl[n * 128 + kc * 4];
            acc0[n] += w0.x * xv.x + w0.y * xv.y + w0.z * xv.z + w0.w * xv.w;
            acc1[n] += w1.x * xv.x + w1.y * xv.y + w1.z * xv.z + w1.w * xv.w;
        }
    }
    const float bi0 = b1[t], bi1 = b1[t + 128];
    #pragma unroll
    for (int n = 0; n < 16; ++n) {
        hidl[n * 256 + t]       = fmaxf(acc0[n] + bi0, 0.f);
        hidl[n * 256 + 128 + t] = fmaxf(acc1[n] + bi1, 0.f);
    }
    __syncthreads();

    float acc2[16];
    #pragma unroll
    for (int n = 0; n < 16; ++n) acc2[n] = 0.f;
    const float* w2p = W2 + (size_t)t * 256;
    for (int kc = 0; kc < 64; ++kc) {
        const float4 w = *(const float4*)(w2p + kc * 4);
        #pragma unroll
        for (int n = 0; n < 16; ++n) {
            const float4 hv = *(const float4*)&hidl[n * 256 + kc * 4];
            acc2[n] += w.x * hv.x + w.y * hv.y + w.z * hv.z + w.w * hv.w;
        }
    }
    const float bi2 = b2[t];
    float s = 0.f, sq = 0.f;
    float* zo = zb + (size_t)n0 * 128 + t;
    #pragma unroll
    for (int n = 0; n < 16; ++n) {
        const float z = xnl[n * 128 + t] + acc2[n] + bi2;
        zo[(size_t)n * 128] = z;
        s += z; sq += z * z;
    }
    atomicAdd(&stat2[t], s);
    atomicAdd(&stat2[128 + t], sq);
}

// ---------------------------------------------------------- final BN -------
__global__ void final_bn(const float4* __restrict__ zb, const float* __restrict__ pa,
                         const float* __restrict__ pb, float4* __restrict__ out, int total4)
{
    const float4* a4 = (const float4*)pa;
    const float4* b4 = (const float4*)pb;
    const int stride = gridDim.x * blockDim.x;
    for (int i = blockIdx.x * blockDim.x + threadIdx.x; i < total4; i += stride) {
        const float4 z = zb[i];
        const float4 a = a4[i & 31], b = b4[i & 31];
        float4 r;
        r.x = z.x * a.x + b.x; r.y = z.y * a.y + b.y;
        r.z = z.z * a.z + b.z; r.w = z.w * a.w + b.w;
        out[i] = r;
    }
}

// ---------------------------------------------------------------------------
extern "C" void kernel_launch(void* const* d_in, const int* in_sizes, int n_in,
                              void* d_out, int out_size, void* d_ws, size_t ws_size,
                              hipStream_t stream)
{
    const float* h   = (const float*)d_in[0];
    const int*   ei  = (const int*)  d_in[1];
    const float* ea  = (const float*)d_in[2];
    const float* Wq  = (const float*)d_in[3];
    const float* Wk  = (const float*)d_in[4];
    const float* Wv  = (const float*)d_in[5];
    const float* We  = (const float*)d_in[6];
    const float* Wb  = (const float*)d_in[7];
    const float* bbv = (const float*)d_in[8];
    const float* g1  = (const float*)d_in[9];
    const float* be1 = (const float*)d_in[10];
    const float* W1  = (const float*)d_in[11];
    const float* b1  = (const float*)d_in[12];
    const float* W2  = (const float*)d_in[13];
    const float* b2  = (const float*)d_in[14];
    const float* g2  = (const float*)d_in[15];
    const float* be2 = (const float*)d_in[16];
    float* out = (float*)d_out;

    const int N   = in_sizes[0] / 128;
    const int EDG = in_sizes[1] / 2;
    const int NB  = (N + 1023) / 1024;
    const size_t nd = (size_t)N * 128;

    float* ws = (float*)d_ws;
    const size_t Qo  = 0;                       // Qb; reused as x after edge_score
    const size_t Ko  = nd;                      // Kb; reused as z after gather
    const size_t Vo  = 2 * nd;                  // Vb
    const size_t SCo = 3 * nd;                  // score (EDG*8 f32)
    const size_t ELo = SCo + (size_t)EDG * 8;   // elist (EDG int2)
    const size_t OFo = ELo + (size_t)EDG * 2;   // offs (N+1 ints)
    const size_t CUo = OFo + (size_t)(N + 2);   // counts/cursor (N ints)
    const size_t BSo = CUo + (size_t)N;         // block sums (NB ints)
    const size_t BBo = BSo + (size_t)NB;        // block bases (NB ints)
    const size_t STo = BBo + (size_t)NB + 2;    // stats: 512 f32
    const size_t PAR = STo + 512;               // bn params: 512 f32

    int*  cnt   = (int*)(ws + CUo);
    int*  offs  = (int*)(ws + OFo);
    int*  bsum  = (int*)(ws + BSo);
    int*  bbase = (int*)(ws + BBo);
    int2* elist = (int2*)(ws + ELo);

    hipMemsetAsync(cnt, 0, (size_t)N * sizeof(int), stream);
    hipMemsetAsync(ws + STo, 0, 512 * sizeof(float), stream);

    qkv_kernel<<<N / 16, 128, 0, stream>>>(h, Wq, Wk, Wv, ws + Qo, ws + Ko, ws + Vo);

    hist_kernel<<<1024, 256, 0, stream>>>(ei, cnt, EDG);
    scan_a<<<NB, 1024, 0, stream>>>(cnt, bsum, N);
    scan_b<<<1, 64, 0, stream>>>(bsum, bbase, offs, NB, N);
    scan_c<<<NB, 1024, 0, stream>>>(cnt, bbase, offs, N);
    hipMemsetAsync(cnt, 0, (size_t)N * sizeof(int), stream);
    scatter_kernel<<<1024, 256, 0, stream>>>(ei, offs, cnt, elist, EDG);

    edge_score<<<(EDG + 255) / 256, 256, 0, stream>>>(ei, ea, We, Wb, bbv,
                                                      ws + Qo, ws + Ko,
                                                      ws + SCo, EDG);

    gather_kernel<<<(N + 3) / 4, 256, 0, stream>>>(elist, offs, ws + SCo, ws + Vo,
                                                   h, ws + Qo, ws + STo, N);

    bn_params<<<1, 128, 0, stream>>>(ws + STo, ws + STo + 128, g1, be1,
                                     ws + PAR, ws + PAR + 128, 1.0f / (float)N);
    ffn_kernel<<<N / 16, 128, 0, stream>>>(ws + Qo, W1, b1, W2, b2, ws + PAR,
                                           ws + Ko, ws + STo + 256);
    bn_params<<<1, 128, 0, stream>>>(ws + STo + 256, ws + STo + 384, g2, be2,
                                     ws + PAR + 256, ws + PAR + 384, 1.0f / (float)N);
    final_bn<<<1024, 256, 0, stream>>>((const float4*)(ws + Ko), ws + PAR + 256,
                                       ws + PAR + 384, (float4*)out, N * 32);
}

// Round 4
// 1392.531 us; speedup vs baseline: 4.5569x; 1.0123x over previous
//
#include <hip/hip_runtime.h>
#include <math.h>

typedef __attribute__((ext_vector_type(8))) short bf16x8;
typedef __attribute__((ext_vector_type(4))) short bf16x4;
typedef __attribute__((ext_vector_type(4))) float f32x4;

static __device__ __forceinline__ unsigned short f2bf(float x){
    union{float f; unsigned u;} v; v.f = x;
    unsigned r = v.u + 0x7fffu + ((v.u >> 16) & 1u);
    return (unsigned short)(r >> 16);
}
static __device__ __forceinline__ unsigned cvtpk(float lo, float hi){
    unsigned r;
    asm("v_cvt_pk_bf16_f32 %0, %1, %2" : "=v"(r) : "v"(lo), "v"(hi));
    return r;
}

// ---------------------------------------------------------------- QKV ------
__global__ __launch_bounds__(128)
void qkv_kernel(const float* __restrict__ h,
                const float* __restrict__ Wq, const float* __restrict__ Wk,
                const float* __restrict__ Wv,
                float* __restrict__ Qb, float* __restrict__ Kb, float* __restrict__ Vb)
{
    __shared__ float hl[16 * 128];
    const int t  = threadIdx.x;
    const int n0 = blockIdx.x * 16;

    const float4* hg4 = (const float4*)(h + (size_t)n0 * 128);
    float4* hl4 = (float4*)hl;
    #pragma unroll
    for (int i = 0; i < 4; ++i) hl4[i * 128 + t] = hg4[i * 128 + t];
    __syncthreads();

    #pragma unroll
    for (int m = 0; m < 3; ++m) {
        const float* W = (m == 0 ? Wq : (m == 1 ? Wk : Wv)) + t * 128;
        float*       o = (m == 0 ? Qb : (m == 1 ? Kb : Vb)) + (size_t)n0 * 128 + t;
        float acc[16];
        #pragma unroll
        for (int n = 0; n < 16; ++n) acc[n] = 0.f;
        for (int kc = 0; kc < 32; ++kc) {
            const float4 w = *(const float4*)(W + kc * 4);
            #pragma unroll
            for (int n = 0; n < 16; ++n) {
                const float4 x = *(const float4*)&hl[n * 128 + kc * 4];
                acc[n] += w.x * x.x + w.y * x.y + w.z * x.z + w.w * x.w;
            }
        }
        #pragma unroll
        for (int n = 0; n < 16; ++n) o[(size_t)n * 128] = acc[n];
    }
}

// ------------------------------------------------------------- CSR build ---
__global__ void hist_kernel(const int* __restrict__ ei, int* __restrict__ cnt, int EDG)
{
    const int stride = gridDim.x * blockDim.x;
    for (int e = blockIdx.x * blockDim.x + threadIdx.x; e < EDG; e += stride)
        atomicAdd(&cnt[ei[EDG + e]], 1);
}

__global__ __launch_bounds__(1024)
void scan_a(const int* __restrict__ cnt, int* __restrict__ bsum, int n)
{
    __shared__ int tmp[1024];
    const int t = threadIdx.x;
    const int i = blockIdx.x * 1024 + t;
    tmp[t] = (i < n) ? cnt[i] : 0;
    __syncthreads();
    for (int d = 512; d > 0; d >>= 1) {
        if (t < d) tmp[t] += tmp[t + d];
        __syncthreads();
    }
    if (t == 0) bsum[blockIdx.x] = tmp[0];
}

__global__ void scan_b(const int* __restrict__ bsum, int* __restrict__ bbase,
                       int* __restrict__ offs, int nb, int n)
{
    if (threadIdx.x == 0) {
        int run = 0;
        for (int b = 0; b < nb; ++b) { bbase[b] = run; run += bsum[b]; }
        offs[n] = run;
    }
}

__global__ __launch_bounds__(1024)
void scan_c(const int* __restrict__ cnt, const int* __restrict__ bbase,
            int* __restrict__ offs, int n)
{
    __shared__ int tmp[1024];
    const int t = threadIdx.x;
    const int i = blockIdx.x * 1024 + t;
    const int v = (i < n) ? cnt[i] : 0;
    tmp[t] = v;
    __syncthreads();
    for (int d = 1; d < 1024; d <<= 1) {
        const int a = (t >= d) ? tmp[t - d] : 0;
        __syncthreads();
        tmp[t] += a;
        __syncthreads();
    }
    if (i < n) offs[i] = bbase[blockIdx.x] + tmp[t] - v;
}

// consumes cnt (atomicSub -> ends at 0); emits src-only list + per-edge CSR pos
__global__ void scatter_kernel(const int* __restrict__ ei, const int* __restrict__ offs,
                               int* __restrict__ cnt, int* __restrict__ srcl,
                               int* __restrict__ posA, int EDG)
{
    const int stride = gridDim.x * blockDim.x;
    for (int e = blockIdx.x * blockDim.x + threadIdx.x; e < EDG; e += stride) {
        const int d = ei[EDG + e];
        const int p = atomicSub(&cnt[d], 1) - 1;
        const int pos = offs[d] + p;
        srcl[pos] = ei[e];
        posA[e] = pos;
    }
}

// ----------------------------------------------------- edge scores (MFMA) --
// Barrier-free main loop: We/Wb staged once in LDS (bf16, XOR-swizzled);
// eattr B-fragments loaded per-lane global->reg (cvt_pk to bf16); K/Q
// gathered per-lane fp32 in the epilogue. Scores written in CSR order.
__global__ __launch_bounds__(256, 4)
void edge_score(const int* __restrict__ ei, const float* __restrict__ eattr,
                const float* __restrict__ We, const float* __restrict__ Wb,
                const float* __restrict__ bbv, const int* __restrict__ posA,
                const float* __restrict__ Qb, const float* __restrict__ Kb,
                float* __restrict__ scoreP, int EDG)
{
    __shared__ unsigned short WeB[128 * 128];  // 32 KB (d,k): byte d*256 + ((2k)^((d&7)<<4))
    __shared__ unsigned short WbB[16 * 128];   // 4 KB, rows 8..15 zero
    const int t = threadIdx.x;

    #pragma unroll
    for (int i = 0; i < 16; ++i) {
        const int idx4 = i * 256 + t;              // 0..4095
        const int d = idx4 >> 5, k0 = (idx4 & 31) * 4;
        const float4 w = *(const float4*)&We[d * 128 + k0];
        bf16x4 p;
        p[0] = (short)f2bf(w.x); p[1] = (short)f2bf(w.y);
        p[2] = (short)f2bf(w.z); p[3] = (short)f2bf(w.w);
        *(bf16x4*)((char*)WeB + d * 256 + ((2 * k0) ^ ((d & 7) << 4))) = p;
    }
    #pragma unroll
    for (int i = 0; i < 8; ++i) {
        const int idx = i * 256 + t;               // 0..2047
        const int r = idx >> 7, k = idx & 127;
        const unsigned short v = (r < 8) ? f2bf(Wb[r * 128 + k]) : (unsigned short)0;
        *(unsigned short*)((char*)WbB + r * 256 + ((2 * k) ^ ((r & 7) << 4))) = v;
    }
    __syncthreads();                                // the only barrier

    const int l = t & 63, w = t >> 6;
    const int eloc = l & 15;
    const int g4 = l >> 4;                          // k-octet selector
    float bb[8];
    #pragma unroll
    for (int h = 0; h < 8; ++h) bb[h] = bbv[h];

    for (int it = 0; it < 4; ++it) {
        const int ge  = blockIdx.x * 256 + it * 64 + w * 16 + eloc;
        const int gec = (ge < EDG) ? ge : (EDG - 1);

        // ---- per-lane B-fragment loads (this lane's edge row, its k-octets)
        const float* ep = &eattr[(size_t)gec * 128 + g4 * 8];
        float4 ea0[4], ea1[4];
        #pragma unroll
        for (int ks = 0; ks < 4; ++ks) {
            ea0[ks] = *(const float4*)(ep + ks * 32);
            ea1[ks] = *(const float4*)(ep + ks * 32 + 4);
        }
        // ---- src/dst/pos (issue early; overlap MFMAs) ----
        const int s  = ei[gec];
        const int d  = ei[EDG + gec];
        const int pp = posA[gec];
        const float* kr = &Kb[(size_t)s * 128 + g4 * 4];
        const float* qr = &Qb[(size_t)d * 128 + g4 * 4];

        // ---- MFMA: 8 head tiles + 1 bias tile, K=128 ----
        f32x4 acc[8], accb;
        #pragma unroll
        for (int h = 0; h < 8; ++h) acc[h] = (f32x4){0.f, 0.f, 0.f, 0.f};
        accb = (f32x4){0.f, 0.f, 0.f, 0.f};

        const int kb_l = g4 * 16;
        #pragma unroll
        for (int ks = 0; ks < 4; ++ks) {
            union { unsigned u[4]; bf16x8 v; } fr;
            fr.u[0] = cvtpk(ea0[ks].x, ea0[ks].y);
            fr.u[1] = cvtpk(ea0[ks].z, ea0[ks].w);
            fr.u[2] = cvtpk(ea1[ks].x, ea1[ks].y);
            fr.u[3] = cvtpk(ea1[ks].z, ea1[ks].w);
            const int kb = ks * 64 + kb_l;
            const bf16x8 abf = *(const bf16x8*)((char*)WbB + eloc * 256 + (kb ^ ((eloc & 7) << 4)));
            accb = __builtin_amdgcn_mfma_f32_16x16x32_bf16(abf, fr.v, accb, 0, 0, 0);
            #pragma unroll
            for (int h = 0; h < 8; ++h) {
                const int ar = h * 16 + eloc;
                const bf16x8 af = *(const bf16x8*)((char*)WeB + ar * 256 + (kb ^ ((ar & 7) << 4)));
                acc[h] = __builtin_amdgcn_mfma_f32_16x16x32_bf16(af, fr.v, acc[h], 0, 0, 0);
            }
        }

        // ---- epilogue: fp32 K*Q dot vs acc, cross-lane reduce, exp, store --
        float scv[8];
        #pragma unroll
        for (int h = 0; h < 8; ++h) {
            const float4 kk = *(const float4*)(kr + h * 16);
            const float4 qq = *(const float4*)(qr + h * 16);
            float m = acc[h][0] * (kk.x * qq.x) + acc[h][1] * (kk.y * qq.y)
                    + acc[h][2] * (kk.z * qq.z) + acc[h][3] * (kk.w * qq.w);
            m += __shfl_xor(m, 16);
            m += __shfl_xor(m, 32);
            const float eb = __shfl(accb[h & 3], ((h >> 2) << 4) | eloc);
            float sc = m * 0.25f + eb + bb[h];
            scv[h] = expf(fminf(fmaxf(sc, -5.f), 5.f));
        }
        if (l < 16 && ge < EDG) {
            float4 s0 = {scv[0], scv[1], scv[2], scv[3]};
            float4 s1 = {scv[4], scv[5], scv[6], scv[7]};
            *(float4*)&scoreP[(size_t)pp * 8]     = s0;
            *(float4*)&scoreP[(size_t)pp * 8 + 4] = s1;
        }
    }
}

// ------------------------------------------------- gather + resid + stats --
// Wave per node; half-waves process alternating edges; float4 V loads;
// scores read in CSR order (contiguous).
__global__ __launch_bounds__(256)
void gather_kernel(const int* __restrict__ srcl, const int* __restrict__ offs,
                   const float* __restrict__ score, const float* __restrict__ Vb,
                   const float* __restrict__ h, float* __restrict__ x,
                   float* __restrict__ stat, int N)
{
    __shared__ float ssl[4][128], sql[4][128];
    const int t = threadIdx.x, w = t >> 6, l = t & 63;
    const int half = l >> 5, q = l & 31;
    const int node = blockIdx.x * 4 + w;

    float4 acc = {0.f, 0.f, 0.f, 0.f};
    float z = 0.f;
    if (node < N) {
        const int beg = offs[node], end = offs[node + 1];
        for (int i = beg + half; i < end; i += 2) {
            const int src = srcl[i];
            const float sc = score[(size_t)i * 8 + (q >> 2)];
            const float4 v = *(const float4*)&Vb[(size_t)src * 128 + 4 * q];
            acc.x += v.x * sc; acc.y += v.y * sc;
            acc.z += v.z * sc; acc.w += v.w * sc;
            z += sc;
        }
    }
    acc.x += __shfl_xor(acc.x, 32); acc.y += __shfl_xor(acc.y, 32);
    acc.z += __shfl_xor(acc.z, 32); acc.w += __shfl_xor(acc.w, 32);
    z     += __shfl_xor(z, 32);

    float4 xv = {0.f, 0.f, 0.f, 0.f};
    if (half == 0) {
        if (node < N) {
            const float inv = 1.f / (z + 1e-6f);
            const float4 hv = *(const float4*)&h[(size_t)node * 128 + 4 * q];
            xv.x = hv.x + acc.x * inv; xv.y = hv.y + acc.y * inv;
            xv.z = hv.z + acc.z * inv; xv.w = hv.w + acc.w * inv;
            *(float4*)&x[(size_t)node * 128 + 4 * q] = xv;
        }
        *(float4*)&ssl[w][4 * q] = xv;
        float4 sq2 = {xv.x * xv.x, xv.y * xv.y, xv.z * xv.z, xv.w * xv.w};
        *(float4*)&sql[w][4 * q] = sq2;
    }
    __syncthreads();
    if (t < 128) {
        atomicAdd(&stat[t],       ssl[0][t] + ssl[1][t] + ssl[2][t] + ssl[3][t]);
        atomicAdd(&stat[128 + t], sql[0][t] + sql[1][t] + sql[2][t] + sql[3][t]);
    }
}

// ---------------------------------------------------------- BN params ------
__global__ void bn_params(const float* __restrict__ sum, const float* __restrict__ sumsq,
                          const float* __restrict__ gamma, const float* __restrict__ beta,
                          float* __restrict__ a, float* __restrict__ b, float invn)
{
    const int c = threadIdx.x;
    const float mean = sum[c] * invn;
    const float var  = sumsq[c] * invn - mean * mean;
    const float sc   = gamma[c] * rsqrtf(var + 1e-5f);
    a[c] = sc;
    b[c] = beta[c] - mean * sc;
}

// ---------------------------------------------------------------- FFN ------
__global__ __launch_bounds__(128)
void ffn_kernel(const float* __restrict__ x, const float* __restrict__ W1,
                const float* __restrict__ b1, const float* __restrict__ W2,
                const float* __restrict__ b2, const float* __restrict__ par,
                float* __restrict__ zb, float* __restrict__ stat2)
{
    __shared__ float xnl[16 * 128];
    __shared__ float hidl[16 * 256];
    const int t  = threadIdx.x;
    const int n0 = blockIdx.x * 16;

    const float4* xg4 = (const float4*)(x + (size_t)n0 * 128);
    const float4* a4  = (const float4*)par;
    const float4* bv4 = (const float4*)(par + 128);
    float4* xnl4 = (float4*)xnl;
    #pragma unroll
    for (int i = 0; i < 4; ++i) {
        const int idx = i * 128 + t;
        const float4 xv = xg4[idx];
        const float4 av = a4[idx & 31], bv = bv4[idx & 31];
        float4 r;
        r.x = xv.x * av.x + bv.x; r.y = xv.y * av.y + bv.y;
        r.z = xv.z * av.z + bv.z; r.w = xv.w * av.w + bv.w;
        xnl4[idx] = r;
    }
    __syncthreads();

    float acc0[16], acc1[16];
    #pragma unroll
    for (int n = 0; n < 16; ++n) { acc0[n] = 0.f; acc1[n] = 0.f; }
    const float* w0p = W1 + (size_t)t * 128;
    const float* w1p = W1 + (size_t)(t + 128) * 128;
    for (int kc = 0; kc < 32; ++kc) {
        const float4 w0 = *(const float4*)(w0p + kc * 4);
        const float4 w1 = *(const float4*)(w1p + kc * 4);
        #pragma unroll
        for (int n = 0; n < 16; ++n) {
            const float4 xv = *(const float4*)&xnl[n * 128 + kc * 4];
            acc0[n] += w0.x * xv.x + w0.y * xv.y + w0.z * xv.z + w0.w * xv.w;
            acc1[n] += w1.x * xv.x + w1.y * xv.y + w1.z * xv.z + w1.w * xv.w;
        }
    }
    const float bi0 = b1[t], bi1 = b1[t + 128];
    #pragma unroll
    for (int n = 0; n < 16; ++n) {
        hidl[n * 256 + t]       = fmaxf(acc0[n] + bi0, 0.f);
        hidl[n * 256 + 128 + t] = fmaxf(acc1[n] + bi1, 0.f);
    }
    __syncthreads();

    float acc2[16];
    #pragma unroll
    for (int n = 0; n < 16; ++n) acc2[n] = 0.f;
    const float* w2p = W2 + (size_t)t * 256;
    for (int kc = 0; kc < 64; ++kc) {
        const float4 w = *(const float4*)(w2p + kc * 4);
        #pragma unroll
        for (int n = 0; n < 16; ++n) {
            const float4 hv = *(const float4*)&hidl[n * 256 + kc * 4];
            acc2[n] += w.x * hv.x + w.y * hv.y + w.z * hv.z + w.w * hv.w;
        }
    }
    const float bi2 = b2[t];
    float s = 0.f, sq = 0.f;
    float* zo = zb + (size_t)n0 * 128 + t;
    #pragma unroll
    for (int n = 0; n < 16; ++n) {
        const float z = xnl[n * 128 + t] + acc2[n] + bi2;
        zo[(size_t)n * 128] = z;
        s += z; sq += z * z;
    }
    atomicAdd(&stat2[t], s);
    atomicAdd(&stat2[128 + t], sq);
}

// ---------------------------------------------------------- final BN -------
__global__ void final_bn(const float4* __restrict__ zb, const float* __restrict__ pa,
                         const float* __restrict__ pb, float4* __restrict__ out, int total4)
{
    const float4* a4 = (const float4*)pa;
    const float4* b4 = (const float4*)pb;
    const int stride = gridDim.x * blockDim.x;
    for (int i = blockIdx.x * blockDim.x + threadIdx.x; i < total4; i += stride) {
        const float4 z = zb[i];
        const float4 a = a4[i & 31], b = b4[i & 31];
        float4 r;
        r.x = z.x * a.x + b.x; r.y = z.y * a.y + b.y;
        r.z = z.z * a.z + b.z; r.w = z.w * a.w + b.w;
        out[i] = r;
    }
}

// ---------------------------------------------------------------------------
extern "C" void kernel_launch(void* const* d_in, const int* in_sizes, int n_in,
                              void* d_out, int out_size, void* d_ws, size_t ws_size,
                              hipStream_t stream)
{
    const float* h   = (const float*)d_in[0];
    const int*   ei  = (const int*)  d_in[1];
    const float* ea  = (const float*)d_in[2];
    const float* Wq  = (const float*)d_in[3];
    const float* Wk  = (const float*)d_in[4];
    const float* Wv  = (const float*)d_in[5];
    const float* We  = (const float*)d_in[6];
    const float* Wb  = (const float*)d_in[7];
    const float* bbv = (const float*)d_in[8];
    const float* g1  = (const float*)d_in[9];
    const float* be1 = (const float*)d_in[10];
    const float* W1  = (const float*)d_in[11];
    const float* b1  = (const float*)d_in[12];
    const float* W2  = (const float*)d_in[13];
    const float* b2  = (const float*)d_in[14];
    const float* g2  = (const float*)d_in[15];
    const float* be2 = (const float*)d_in[16];
    float* out = (float*)d_out;

    const int N   = in_sizes[0] / 128;
    const int EDG = in_sizes[1] / 2;
    const int NB  = (N + 1023) / 1024;
    const size_t nd = (size_t)N * 128;
    auto al8 = [](size_t v){ return (v + 7) & ~(size_t)7; };

    float* ws = (float*)d_ws;
    const size_t Qo  = 0;                            // Qb; reused as x after edge_score
    const size_t Ko  = nd;                           // Kb; reused as z after gather
    const size_t Vo  = 2 * nd;                       // Vb
    const size_t SCo = 3 * nd;                       // score, CSR order (EDG*8 f32)
    const size_t SRo = SCo + (size_t)EDG * 8;        // srcl (EDG int)
    const size_t POo = SRo + (size_t)EDG;            // posA (EDG int)
    const size_t OFo = POo + (size_t)EDG;            // offs (N+1 int)
    const size_t CUo = al8(OFo + (size_t)N + 8);     // counts (N int)
    const size_t BSo = al8(CUo + (size_t)N);         // block sums (NB int)
    const size_t BBo = al8(BSo + (size_t)NB);        // block bases (NB int)
    const size_t STo = al8(BBo + (size_t)NB);        // stats: 512 f32
    const size_t PAR = STo + 512;                    // bn params: 512 f32

    int* cnt   = (int*)(ws + CUo);
    int* offs  = (int*)(ws + OFo);
    int* bsum  = (int*)(ws + BSo);
    int* bbase = (int*)(ws + BBo);
    int* srcl  = (int*)(ws + SRo);
    int* posA  = (int*)(ws + POo);

    hipMemsetAsync(cnt, 0, (size_t)N * sizeof(int), stream);
    hipMemsetAsync(ws + STo, 0, 512 * sizeof(float), stream);

    qkv_kernel<<<N / 16, 128, 0, stream>>>(h, Wq, Wk, Wv, ws + Qo, ws + Ko, ws + Vo);

    hist_kernel<<<1024, 256, 0, stream>>>(ei, cnt, EDG);
    scan_a<<<NB, 1024, 0, stream>>>(cnt, bsum, N);
    scan_b<<<1, 64, 0, stream>>>(bsum, bbase, offs, NB, N);
    scan_c<<<NB, 1024, 0, stream>>>(cnt, bbase, offs, N);
    scatter_kernel<<<1024, 256, 0, stream>>>(ei, offs, cnt, srcl, posA, EDG);

    edge_score<<<(EDG + 255) / 256, 256, 0, stream>>>(ei, ea, We, Wb, bbv, posA,
                                                      ws + Qo, ws + Ko,
                                                      ws + SCo, EDG);

    gather_kernel<<<(N + 3) / 4, 256, 0, stream>>>(srcl, offs, ws + SCo, ws + Vo,
                                                   h, ws + Qo, ws + STo, N);

    bn_params<<<1, 128, 0, stream>>>(ws + STo, ws + STo + 128, g1, be1,
                                     ws + PAR, ws + PAR + 128, 1.0f / (float)N);
    ffn_kernel<<<N / 16, 128, 0, stream>>>(ws + Qo, W1, b1, W2, b2, ws + PAR,
                                           ws + Ko, ws + STo + 256);
    bn_params<<<1, 128, 0, stream>>>(ws + STo + 256, ws + STo + 384, g2, be2,
                                     ws + PAR + 256, ws + PAR + 384, 1.0f / (float)N);
    final_bn<<<1024, 256, 0, stream>>>((const float4*)(ws + Ko), ws + PAR + 256,
                                       ws + PAR + 384, (float4*)out, N * 32);
}

// Round 5
// 1345.666 us; speedup vs baseline: 4.7156x; 1.0348x over previous
//
#include <hip/hip_runtime.h>
#include <math.h>

typedef __attribute__((ext_vector_type(8))) short bf16x8;
typedef __attribute__((ext_vector_type(4))) short bf16x4;
typedef __attribute__((ext_vector_type(4))) float f32x4;

static __device__ __forceinline__ unsigned short f2bf(float x){
    union{float f; unsigned u;} v; v.f = x;
    unsigned r = v.u + 0x7fffu + ((v.u >> 16) & 1u);
    return (unsigned short)(r >> 16);
}
static __device__ __forceinline__ unsigned cvtpk(float lo, float hi){
    unsigned r;
    asm("v_cvt_pk_bf16_f32 %0, %1, %2" : "=v"(r) : "v"(lo), "v"(hi));
    return r;
}

// ---------------------------------------------------------------- QKV ------
__global__ __launch_bounds__(128)
void qkv_kernel(const float* __restrict__ h,
                const float* __restrict__ Wq, const float* __restrict__ Wk,
                const float* __restrict__ Wv,
                float* __restrict__ Qb, float* __restrict__ Kb, float* __restrict__ Vb)
{
    __shared__ float hl[16 * 128];
    const int t  = threadIdx.x;
    const int n0 = blockIdx.x * 16;

    const float4* hg4 = (const float4*)(h + (size_t)n0 * 128);
    float4* hl4 = (float4*)hl;
    #pragma unroll
    for (int i = 0; i < 4; ++i) hl4[i * 128 + t] = hg4[i * 128 + t];
    __syncthreads();

    #pragma unroll
    for (int m = 0; m < 3; ++m) {
        const float* W = (m == 0 ? Wq : (m == 1 ? Wk : Wv)) + t * 128;
        float*       o = (m == 0 ? Qb : (m == 1 ? Kb : Vb)) + (size_t)n0 * 128 + t;
        float acc[16];
        #pragma unroll
        for (int n = 0; n < 16; ++n) acc[n] = 0.f;
        for (int kc = 0; kc < 32; ++kc) {
            const float4 w = *(const float4*)(W + kc * 4);
            #pragma unroll
            for (int n = 0; n < 16; ++n) {
                const float4 x = *(const float4*)&hl[n * 128 + kc * 4];
                acc[n] += w.x * x.x + w.y * x.y + w.z * x.z + w.w * x.w;
            }
        }
        #pragma unroll
        for (int n = 0; n < 16; ++n) o[(size_t)n * 128] = acc[n];
    }
}

// ------------------------------------------------------------- CSR build ---
__global__ void hist_kernel(const int* __restrict__ ei, int* __restrict__ cnt, int EDG)
{
    const int stride = gridDim.x * blockDim.x;
    for (int e = blockIdx.x * blockDim.x + threadIdx.x; e < EDG; e += stride)
        atomicAdd(&cnt[ei[EDG + e]], 1);
}

__global__ __launch_bounds__(1024)
void scan_a(const int* __restrict__ cnt, int* __restrict__ bsum, int n)
{
    __shared__ int tmp[1024];
    const int t = threadIdx.x;
    const int i = blockIdx.x * 1024 + t;
    tmp[t] = (i < n) ? cnt[i] : 0;
    __syncthreads();
    for (int d = 512; d > 0; d >>= 1) {
        if (t < d) tmp[t] += tmp[t + d];
        __syncthreads();
    }
    if (t == 0) bsum[blockIdx.x] = tmp[0];
}

__global__ void scan_b(const int* __restrict__ bsum, int* __restrict__ bbase,
                       int* __restrict__ offs, int nb, int n)
{
    if (threadIdx.x == 0) {
        int run = 0;
        for (int b = 0; b < nb; ++b) { bbase[b] = run; run += bsum[b]; }
        offs[n] = run;
    }
}

__global__ __launch_bounds__(1024)
void scan_c(const int* __restrict__ cnt, const int* __restrict__ bbase,
            int* __restrict__ offs, int n)
{
    __shared__ int tmp[1024];
    const int t = threadIdx.x;
    const int i = blockIdx.x * 1024 + t;
    const int v = (i < n) ? cnt[i] : 0;
    tmp[t] = v;
    __syncthreads();
    for (int d = 1; d < 1024; d <<= 1) {
        const int a = (t >= d) ? tmp[t - d] : 0;
        __syncthreads();
        tmp[t] += a;
        __syncthreads();
    }
    if (i < n) offs[i] = bbase[blockIdx.x] + tmp[t] - v;
}

// consumes cnt (atomicSub -> ends at 0); emits (src, edge) list in CSR order
__global__ void scatter_kernel(const int* __restrict__ ei, const int* __restrict__ offs,
                               int* __restrict__ cnt, int2* __restrict__ elist, int EDG)
{
    const int stride = gridDim.x * blockDim.x;
    for (int e = blockIdx.x * blockDim.x + threadIdx.x; e < EDG; e += stride) {
        const int d = ei[EDG + e];
        const int p = atomicSub(&cnt[d], 1) - 1;
        int2 v; v.x = ei[e]; v.y = e;
        elist[offs[d] + p] = v;
    }
}

// ----------------------------------------------------- edge scores (MFMA) --
// Barrier-free main loop: We/Wb staged once in LDS (bf16, XOR-swizzled);
// eattr B-fragments loaded per-lane global->reg (cvt_pk to bf16); K/Q
// gathered per-lane fp32 in the epilogue. Scores written in EDGE order.
__global__ __launch_bounds__(256, 3)
void edge_score(const int* __restrict__ ei, const float* __restrict__ eattr,
                const float* __restrict__ We, const float* __restrict__ Wb,
                const float* __restrict__ bbv,
                const float* __restrict__ Qb, const float* __restrict__ Kb,
                float* __restrict__ scoreP, int EDG)
{
    __shared__ unsigned short WeB[128 * 128];  // 32 KB (d,k): byte d*256 + ((2k)^((d&7)<<4))
    __shared__ unsigned short WbB[16 * 128];   // 4 KB, rows 8..15 zero
    const int t = threadIdx.x;

    #pragma unroll
    for (int i = 0; i < 16; ++i) {
        const int idx4 = i * 256 + t;              // 0..4095
        const int d = idx4 >> 5, k0 = (idx4 & 31) * 4;
        const float4 w = *(const float4*)&We[d * 128 + k0];
        bf16x4 p;
        p[0] = (short)f2bf(w.x); p[1] = (short)f2bf(w.y);
        p[2] = (short)f2bf(w.z); p[3] = (short)f2bf(w.w);
        *(bf16x4*)((char*)WeB + d * 256 + ((2 * k0) ^ ((d & 7) << 4))) = p;
    }
    #pragma unroll
    for (int i = 0; i < 8; ++i) {
        const int idx = i * 256 + t;               // 0..2047
        const int r = idx >> 7, k = idx & 127;
        const unsigned short v = (r < 8) ? f2bf(Wb[r * 128 + k]) : (unsigned short)0;
        *(unsigned short*)((char*)WbB + r * 256 + ((2 * k) ^ ((r & 7) << 4))) = v;
    }
    __syncthreads();                                // the only barrier

    const int l = t & 63, w = t >> 6;
    const int eloc = l & 15;
    const int g4 = l >> 4;                          // k-octet selector
    float bb[8];
    #pragma unroll
    for (int h = 0; h < 8; ++h) bb[h] = bbv[h];

    for (int it = 0; it < 4; ++it) {
        const int ge  = blockIdx.x * 256 + it * 64 + w * 16 + eloc;
        const int gec = (ge < EDG) ? ge : (EDG - 1);

        // ---- per-lane B-fragment loads (this lane's edge row, its k-octets)
        const float* ep = &eattr[(size_t)gec * 128 + g4 * 8];
        float4 ea0[4], ea1[4];
        #pragma unroll
        for (int ks = 0; ks < 4; ++ks) {
            ea0[ks] = *(const float4*)(ep + ks * 32);
            ea1[ks] = *(const float4*)(ep + ks * 32 + 4);
        }
        // ---- src/dst (issue early; overlap MFMAs) ----
        const int s  = ei[gec];
        const int d  = ei[EDG + gec];
        const float* kr = &Kb[(size_t)s * 128 + g4 * 4];
        const float* qr = &Qb[(size_t)d * 128 + g4 * 4];

        // ---- MFMA: 8 head tiles + 1 bias tile, K=128 ----
        f32x4 acc[8], accb;
        #pragma unroll
        for (int h = 0; h < 8; ++h) acc[h] = (f32x4){0.f, 0.f, 0.f, 0.f};
        accb = (f32x4){0.f, 0.f, 0.f, 0.f};

        const int kb_l = g4 * 16;
        #pragma unroll
        for (int ks = 0; ks < 4; ++ks) {
            union { unsigned u[4]; bf16x8 v; } fr;
            fr.u[0] = cvtpk(ea0[ks].x, ea0[ks].y);
            fr.u[1] = cvtpk(ea0[ks].z, ea0[ks].w);
            fr.u[2] = cvtpk(ea1[ks].x, ea1[ks].y);
            fr.u[3] = cvtpk(ea1[ks].z, ea1[ks].w);
            const int kb = ks * 64 + kb_l;
            const bf16x8 abf = *(const bf16x8*)((char*)WbB + eloc * 256 + (kb ^ ((eloc & 7) << 4)));
            accb = __builtin_amdgcn_mfma_f32_16x16x32_bf16(abf, fr.v, accb, 0, 0, 0);
            #pragma unroll
            for (int h = 0; h < 8; ++h) {
                const int ar = h * 16 + eloc;
                const bf16x8 af = *(const bf16x8*)((char*)WeB + ar * 256 + (kb ^ ((ar & 7) << 4)));
                acc[h] = __builtin_amdgcn_mfma_f32_16x16x32_bf16(af, fr.v, acc[h], 0, 0, 0);
            }
        }

        // ---- epilogue: fp32 K*Q dot vs acc, cross-lane reduce, exp, store --
        float scv[8];
        #pragma unroll
        for (int h = 0; h < 8; ++h) {
            const float4 kk = *(const float4*)(kr + h * 16);
            const float4 qq = *(const float4*)(qr + h * 16);
            float m = acc[h][0] * (kk.x * qq.x) + acc[h][1] * (kk.y * qq.y)
                    + acc[h][2] * (kk.z * qq.z) + acc[h][3] * (kk.w * qq.w);
            m += __shfl_xor(m, 16);
            m += __shfl_xor(m, 32);
            const float eb = __shfl(accb[h & 3], ((h >> 2) << 4) | eloc);
            float sc = m * 0.25f + eb + bb[h];
            scv[h] = expf(fminf(fmaxf(sc, -5.f), 5.f));
        }
        if (l < 16 && ge < EDG) {
            float4 s0 = {scv[0], scv[1], scv[2], scv[3]};
            float4 s1 = {scv[4], scv[5], scv[6], scv[7]};
            *(float4*)&scoreP[(size_t)ge * 8]     = s0;
            *(float4*)&scoreP[(size_t)ge * 8 + 4] = s1;
        }
    }
}

// ------------------------------------------------- gather + resid + stats --
// Wave per node; half-waves take alternating CSR slots; 4-deep manual
// pipeline: batch elist+score loads, then independent V-row loads.
__global__ __launch_bounds__(256)
void gather_kernel(const int2* __restrict__ elist, const int* __restrict__ offs,
                   const float* __restrict__ score, const float* __restrict__ Vb,
                   const float* __restrict__ h, float* __restrict__ x,
                   float* __restrict__ stat, int N)
{
    __shared__ float ssl[4][128], sql[4][128];
    const int t = threadIdx.x, w = t >> 6, l = t & 63;
    const int half = l >> 5, q = l & 31;
    const int hh = q >> 2;
    const int node = blockIdx.x * 4 + w;

    float4 acc = {0.f, 0.f, 0.f, 0.f};
    float z = 0.f;
    if (node < N) {
        const int beg = offs[node], end = offs[node + 1];
        int i = beg + half;
        for (; i + 6 < end; i += 8) {
            const int2 e0 = elist[i];
            const int2 e1 = elist[i + 2];
            const int2 e2 = elist[i + 4];
            const int2 e3 = elist[i + 6];
            const float s0 = score[(size_t)e0.y * 8 + hh];
            const float s1 = score[(size_t)e1.y * 8 + hh];
            const float s2 = score[(size_t)e2.y * 8 + hh];
            const float s3 = score[(size_t)e3.y * 8 + hh];
            const float4 v0 = *(const float4*)&Vb[(size_t)e0.x * 128 + 4 * q];
            const float4 v1 = *(const float4*)&Vb[(size_t)e1.x * 128 + 4 * q];
            const float4 v2 = *(const float4*)&Vb[(size_t)e2.x * 128 + 4 * q];
            const float4 v3 = *(const float4*)&Vb[(size_t)e3.x * 128 + 4 * q];
            acc.x += v0.x * s0 + v1.x * s1 + v2.x * s2 + v3.x * s3;
            acc.y += v0.y * s0 + v1.y * s1 + v2.y * s2 + v3.y * s3;
            acc.z += v0.z * s0 + v1.z * s1 + v2.z * s2 + v3.z * s3;
            acc.w += v0.w * s0 + v1.w * s1 + v2.w * s2 + v3.w * s3;
            z += s0 + s1 + s2 + s3;
        }
        for (; i < end; i += 2) {
            const int2 se = elist[i];
            const float sc = score[(size_t)se.y * 8 + hh];
            const float4 v = *(const float4*)&Vb[(size_t)se.x * 128 + 4 * q];
            acc.x += v.x * sc; acc.y += v.y * sc;
            acc.z += v.z * sc; acc.w += v.w * sc;
            z += sc;
        }
    }
    acc.x += __shfl_xor(acc.x, 32); acc.y += __shfl_xor(acc.y, 32);
    acc.z += __shfl_xor(acc.z, 32); acc.w += __shfl_xor(acc.w, 32);
    z     += __shfl_xor(z, 32);

    float4 xv = {0.f, 0.f, 0.f, 0.f};
    if (half == 0) {
        if (node < N) {
            const float inv = 1.f / (z + 1e-6f);
            const float4 hv = *(const float4*)&h[(size_t)node * 128 + 4 * q];
            xv.x = hv.x + acc.x * inv; xv.y = hv.y + acc.y * inv;
            xv.z = hv.z + acc.z * inv; xv.w = hv.w + acc.w * inv;
            *(float4*)&x[(size_t)node * 128 + 4 * q] = xv;
        }
        *(float4*)&ssl[w][4 * q] = xv;
        float4 sq2 = {xv.x * xv.x, xv.y * xv.y, xv.z * xv.z, xv.w * xv.w};
        *(float4*)&sql[w][4 * q] = sq2;
    }
    __syncthreads();
    if (t < 128) {
        atomicAdd(&stat[t],       ssl[0][t] + ssl[1][t] + ssl[2][t] + ssl[3][t]);
        atomicAdd(&stat[128 + t], sql[0][t] + sql[1][t] + sql[2][t] + sql[3][t]);
    }
}

// ---------------------------------------------------------- BN params ------
__global__ void bn_params(const float* __restrict__ sum, const float* __restrict__ sumsq,
                          const float* __restrict__ gamma, const float* __restrict__ beta,
                          float* __restrict__ a, float* __restrict__ b, float invn)
{
    const int c = threadIdx.x;
    const float mean = sum[c] * invn;
    const float var  = sumsq[c] * invn - mean * mean;
    const float sc   = gamma[c] * rsqrtf(var + 1e-5f);
    a[c] = sc;
    b[c] = beta[c] - mean * sc;
}

// ---------------------------------------------------------------- FFN ------
__global__ __launch_bounds__(128)
void ffn_kernel(const float* __restrict__ x, const float* __restrict__ W1,
                const float* __restrict__ b1, const float* __restrict__ W2,
                const float* __restrict__ b2, const float* __restrict__ par,
                float* __restrict__ zb, float* __restrict__ stat2)
{
    __shared__ float xnl[16 * 128];
    __shared__ float hidl[16 * 256];
    const int t  = threadIdx.x;
    const int n0 = blockIdx.x * 16;

    const float4* xg4 = (const float4*)(x + (size_t)n0 * 128);
    const float4* a4  = (const float4*)par;
    const float4* bv4 = (const float4*)(par + 128);
    float4* xnl4 = (float4*)xnl;
    #pragma unroll
    for (int i = 0; i < 4; ++i) {
        const int idx = i * 128 + t;
        const float4 xv = xg4[idx];
        const float4 av = a4[idx & 31], bv = bv4[idx & 31];
        float4 r;
        r.x = xv.x * av.x + bv.x; r.y = xv.y * av.y + bv.y;
        r.z = xv.z * av.z + bv.z; r.w = xv.w * av.w + bv.w;
        xnl4[idx] = r;
    }
    __syncthreads();

    float acc0[16], acc1[16];
    #pragma unroll
    for (int n = 0; n < 16; ++n) { acc0[n] = 0.f; acc1[n] = 0.f; }
    const float* w0p = W1 + (size_t)t * 128;
    const float* w1p = W1 + (size_t)(t + 128) * 128;
    for (int kc = 0; kc < 32; ++kc) {
        const float4 w0 = *(const float4*)(w0p + kc * 4);
        const float4 w1 = *(const float4*)(w1p + kc * 4);
        #pragma unroll
        for (int n = 0; n < 16; ++n) {
            const float4 xv = *(const float4*)&xnl[n * 128 + kc * 4];
            acc0[n] += w0.x * xv.x + w0.y * xv.y + w0.z * xv.z + w0.w * xv.w;
            acc1[n] += w1.x * xv.x + w1.y * xv.y + w1.z * xv.z + w1.w * xv.w;
        }
    }
    const float bi0 = b1[t], bi1 = b1[t + 128];
    #pragma unroll
    for (int n = 0; n < 16; ++n) {
        hidl[n * 256 + t]       = fmaxf(acc0[n] + bi0, 0.f);
        hidl[n * 256 + 128 + t] = fmaxf(acc1[n] + bi1, 0.f);
    }
    __syncthreads();

    float acc2[16];
    #pragma unroll
    for (int n = 0; n < 16; ++n) acc2[n] = 0.f;
    const float* w2p = W2 + (size_t)t * 256;
    for (int kc = 0; kc < 64; ++kc) {
        const float4 w = *(const float4*)(w2p + kc * 4);
        #pragma unroll
        for (int n = 0; n < 16; ++n) {
            const float4 hv = *(const float4*)&hidl[n * 256 + kc * 4];
            acc2[n] += w.x * hv.x + w.y * hv.y + w.z * hv.z + w.w * hv.w;
        }
    }
    const float bi2 = b2[t];
    float s = 0.f, sq = 0.f;
    float* zo = zb + (size_t)n0 * 128 + t;
    #pragma unroll
    for (int n = 0; n < 16; ++n) {
        const float z = xnl[n * 128 + t] + acc2[n] + bi2;
        zo[(size_t)n * 128] = z;
        s += z; sq += z * z;
    }
    atomicAdd(&stat2[t], s);
    atomicAdd(&stat2[128 + t], sq);
}

// ---------------------------------------------------------- final BN -------
__global__ void final_bn(const float4* __restrict__ zb, const float* __restrict__ pa,
                         const float* __restrict__ pb, float4* __restrict__ out, int total4)
{
    const float4* a4 = (const float4*)pa;
    const float4* b4 = (const float4*)pb;
    const int stride = gridDim.x * blockDim.x;
    for (int i = blockIdx.x * blockDim.x + threadIdx.x; i < total4; i += stride) {
        const float4 z = zb[i];
        const float4 a = a4[i & 31], b = b4[i & 31];
        float4 r;
        r.x = z.x * a.x + b.x; r.y = z.y * a.y + b.y;
        r.z = z.z * a.z + b.z; r.w = z.w * a.w + b.w;
        out[i] = r;
    }
}

// ---------------------------------------------------------------------------
extern "C" void kernel_launch(void* const* d_in, const int* in_sizes, int n_in,
                              void* d_out, int out_size, void* d_ws, size_t ws_size,
                              hipStream_t stream)
{
    const float* h   = (const float*)d_in[0];
    const int*   ei  = (const int*)  d_in[1];
    const float* ea  = (const float*)d_in[2];
    const float* Wq  = (const float*)d_in[3];
    const float* Wk  = (const float*)d_in[4];
    const float* Wv  = (const float*)d_in[5];
    const float* We  = (const float*)d_in[6];
    const float* Wb  = (const float*)d_in[7];
    const float* bbv = (const float*)d_in[8];
    const float* g1  = (const float*)d_in[9];
    const float* be1 = (const float*)d_in[10];
    const float* W1  = (const float*)d_in[11];
    const float* b1  = (const float*)d_in[12];
    const float* W2  = (const float*)d_in[13];
    const float* b2  = (const float*)d_in[14];
    const float* g2  = (const float*)d_in[15];
    const float* be2 = (const float*)d_in[16];
    float* out = (float*)d_out;

    const int N   = in_sizes[0] / 128;
    const int EDG = in_sizes[1] / 2;
    const int NB  = (N + 1023) / 1024;
    const size_t nd = (size_t)N * 128;
    auto al8 = [](size_t v){ return (v + 7) & ~(size_t)7; };

    float* ws = (float*)d_ws;
    const size_t Qo  = 0;                            // Qb; reused as x after edge_score
    const size_t Ko  = nd;                           // Kb; reused as z after gather
    const size_t Vo  = 2 * nd;                       // Vb
    const size_t SCo = 3 * nd;                       // score, edge order (EDG*8 f32)
    const size_t ELo = SCo + (size_t)EDG * 8;        // elist (EDG int2)
    const size_t OFo = ELo + (size_t)EDG * 2;        // offs (N+1 int)
    const size_t CUo = al8(OFo + (size_t)N + 8);     // counts (N int)
    const size_t BSo = al8(CUo + (size_t)N);         // block sums (NB int)
    const size_t BBo = al8(BSo + (size_t)NB);        // block bases (NB int)
    const size_t STo = al8(BBo + (size_t)NB);        // stats: 512 f32
    const size_t PAR = STo + 512;                    // bn params: 512 f32

    int*  cnt   = (int*)(ws + CUo);
    int*  offs  = (int*)(ws + OFo);
    int*  bsum  = (int*)(ws + BSo);
    int*  bbase = (int*)(ws + BBo);
    int2* elist = (int2*)(ws + ELo);

    hipMemsetAsync(cnt, 0, (size_t)N * sizeof(int), stream);
    hipMemsetAsync(ws + STo, 0, 512 * sizeof(float), stream);

    qkv_kernel<<<N / 16, 128, 0, stream>>>(h, Wq, Wk, Wv, ws + Qo, ws + Ko, ws + Vo);

    hist_kernel<<<1024, 256, 0, stream>>>(ei, cnt, EDG);
    scan_a<<<NB, 1024, 0, stream>>>(cnt, bsum, N);
    scan_b<<<1, 64, 0, stream>>>(bsum, bbase, offs, NB, N);
    scan_c<<<NB, 1024, 0, stream>>>(cnt, bbase, offs, N);
    scatter_kernel<<<1024, 256, 0, stream>>>(ei, offs, cnt, elist, EDG);

    edge_score<<<(EDG + 255) / 256, 256, 0, stream>>>(ei, ea, We, Wb, bbv,
                                                      ws + Qo, ws + Ko,
                                                      ws + SCo, EDG);

    gather_kernel<<<(N + 3) / 4, 256, 0, stream>>>(elist, offs, ws + SCo, ws + Vo,
                                                   h, ws + Qo, ws + STo, N);

    bn_params<<<1, 128, 0, stream>>>(ws + STo, ws + STo + 128, g1, be1,
                                     ws + PAR, ws + PAR + 128, 1.0f / (float)N);
    ffn_kernel<<<N / 16, 128, 0, stream>>>(ws + Qo, W1, b1, W2, b2, ws + PAR,
                                           ws + Ko, ws + STo + 256);
    bn_params<<<1, 128, 0, stream>>>(ws + STo + 256, ws + STo + 384, g2, be2,
                                     ws + PAR + 256, ws + PAR + 384, 1.0f / (float)N);
    final_bn<<<1024, 256, 0, stream>>>((const float4*)(ws + Ko), ws + PAR + 256,
                                       ws + PAR + 384, (float4*)out, N * 32);
}

// Round 6
// 1033.327 us; speedup vs baseline: 6.1410x; 1.3023x over previous
//
#include <hip/hip_runtime.h>
#include <math.h>

typedef __attribute__((ext_vector_type(8))) short bf16x8;
typedef __attribute__((ext_vector_type(4))) short bf16x4;
typedef __attribute__((ext_vector_type(4))) float f32x4;

static __device__ __forceinline__ unsigned short f2bf(float x){
    union{float f; unsigned u;} v; v.f = x;
    unsigned r = v.u + 0x7fffu + ((v.u >> 16) & 1u);
    return (unsigned short)(r >> 16);
}
static __device__ __forceinline__ unsigned cvtpk(float lo, float hi){
    unsigned r;
    asm("v_cvt_pk_bf16_f32 %0, %1, %2" : "=v"(r) : "v"(lo), "v"(hi));
    return r;
}

// ---------------------------------------------------------------- QKV ------
__global__ __launch_bounds__(128)
void qkv_kernel(const float* __restrict__ h,
                const float* __restrict__ Wq, const float* __restrict__ Wk,
                const float* __restrict__ Wv,
                float* __restrict__ Qb, float* __restrict__ Kb, float* __restrict__ Vb)
{
    __shared__ float hl[16 * 128];
    const int t  = threadIdx.x;
    const int n0 = blockIdx.x * 16;

    const float4* hg4 = (const float4*)(h + (size_t)n0 * 128);
    float4* hl4 = (float4*)hl;
    #pragma unroll
    for (int i = 0; i < 4; ++i) hl4[i * 128 + t] = hg4[i * 128 + t];
    __syncthreads();

    #pragma unroll
    for (int m = 0; m < 3; ++m) {
        const float* W = (m == 0 ? Wq : (m == 1 ? Wk : Wv)) + t * 128;
        float*       o = (m == 0 ? Qb : (m == 1 ? Kb : Vb)) + (size_t)n0 * 128 + t;
        float acc[16];
        #pragma unroll
        for (int n = 0; n < 16; ++n) acc[n] = 0.f;
        for (int kc = 0; kc < 32; ++kc) {
            const float4 w = *(const float4*)(W + kc * 4);
            #pragma unroll
            for (int n = 0; n < 16; ++n) {
                const float4 x = *(const float4*)&hl[n * 128 + kc * 4];
                acc[n] += w.x * x.x + w.y * x.y + w.z * x.z + w.w * x.w;
            }
        }
        #pragma unroll
        for (int n = 0; n < 16; ++n) o[(size_t)n * 128] = acc[n];
    }
}

// ------------------------------------------------------------- CSR build ---
__global__ void hist_kernel(const int* __restrict__ ei, int* __restrict__ cnt, int EDG)
{
    const int stride = gridDim.x * blockDim.x;
    for (int e = blockIdx.x * blockDim.x + threadIdx.x; e < EDG; e += stride)
        atomicAdd(&cnt[ei[EDG + e]], 1);
}

__global__ __launch_bounds__(1024)
void scan_a(const int* __restrict__ cnt, int* __restrict__ bsum, int n)
{
    __shared__ int tmp[1024];
    const int t = threadIdx.x;
    const int i = blockIdx.x * 1024 + t;
    tmp[t] = (i < n) ? cnt[i] : 0;
    __syncthreads();
    for (int d = 512; d > 0; d >>= 1) {
        if (t < d) tmp[t] += tmp[t + d];
        __syncthreads();
    }
    if (t == 0) bsum[blockIdx.x] = tmp[0];
}

__global__ void scan_b(const int* __restrict__ bsum, int* __restrict__ bbase,
                       int* __restrict__ offs, int nb, int n)
{
    if (threadIdx.x == 0) {
        int run = 0;
        for (int b = 0; b < nb; ++b) { bbase[b] = run; run += bsum[b]; }
        offs[n] = run;
    }
}

__global__ __launch_bounds__(1024)
void scan_c(const int* __restrict__ cnt, const int* __restrict__ bbase,
            int* __restrict__ offs, int n)
{
    __shared__ int tmp[1024];
    const int t = threadIdx.x;
    const int i = blockIdx.x * 1024 + t;
    const int v = (i < n) ? cnt[i] : 0;
    tmp[t] = v;
    __syncthreads();
    for (int d = 1; d < 1024; d <<= 1) {
        const int a = (t >= d) ? tmp[t - d] : 0;
        __syncthreads();
        tmp[t] += a;
        __syncthreads();
    }
    if (i < n) offs[i] = bbase[blockIdx.x] + tmp[t] - v;
}

// consumes cnt (atomicSub -> ends at 0); emits (src, edge) list in CSR order
__global__ void scatter_kernel(const int* __restrict__ ei, const int* __restrict__ offs,
                               int* __restrict__ cnt, int2* __restrict__ elist, int EDG)
{
    const int stride = gridDim.x * blockDim.x;
    for (int e = blockIdx.x * blockDim.x + threadIdx.x; e < EDG; e += stride) {
        const int d = ei[EDG + e];
        const int p = atomicSub(&cnt[d], 1) - 1;
        int2 v; v.x = ei[e]; v.y = e;
        elist[offs[d] + p] = v;
    }
}

// --------------------------------------- fused edge-score + gather (MFMA) --
// One wave per node (strided). Per 16-edge CSR chunk: per-lane eattr B-frag
// loads, 36 MFMAs vs LDS-resident We/Wb, score epilogue, then immediate
// V[src]*score accumulation via a tiny per-wave LDS redistribution buffer.
// No score intermediate, no second pass, no block barriers in the loop.
__global__ __launch_bounds__(256, 3)
void fused_attn(const float* __restrict__ eattr, const int2* __restrict__ elist,
                const int* __restrict__ offs,
                const float* __restrict__ We, const float* __restrict__ Wb,
                const float* __restrict__ bbv,
                const float* __restrict__ Qb, const float* __restrict__ Kb,
                const float* __restrict__ Vb, const float* __restrict__ h,
                float* __restrict__ x, float* __restrict__ stat, int N, int EDG)
{
    __shared__ unsigned short WeB[128 * 128];  // 32 KB (d,k): byte d*256 + ((2k)^((d&7)<<4))
    __shared__ unsigned short WbB[16 * 128];   // 4 KB, rows 8..15 zero
    __shared__ float scw[4][16][8];            // per-wave score redistribution
    __shared__ int   srw[4][16];               // per-wave src ids
    __shared__ float ssl[4][128];
    __shared__ float sql[4][128];

    const int t = threadIdx.x;
    #pragma unroll
    for (int i = 0; i < 16; ++i) {
        const int idx4 = i * 256 + t;
        const int d = idx4 >> 5, k0 = (idx4 & 31) * 4;
        const float4 wv = *(const float4*)&We[d * 128 + k0];
        bf16x4 p;
        p[0] = (short)f2bf(wv.x); p[1] = (short)f2bf(wv.y);
        p[2] = (short)f2bf(wv.z); p[3] = (short)f2bf(wv.w);
        *(bf16x4*)((char*)WeB + d * 256 + ((2 * k0) ^ ((d & 7) << 4))) = p;
    }
    #pragma unroll
    for (int i = 0; i < 8; ++i) {
        const int idx = i * 256 + t;
        const int r = idx >> 7, k = idx & 127;
        const unsigned short v = (r < 8) ? f2bf(Wb[r * 128 + k]) : (unsigned short)0;
        *(unsigned short*)((char*)WbB + r * 256 + ((2 * k) ^ ((r & 7) << 4))) = v;
    }
    __syncthreads();                            // WeB/WbB ready; read-only after

    const int l = t & 63, w = t >> 6;
    const int eloc = l & 15, g4 = l >> 4;
    const int hh_l = l >> 3;                    // head owning dims (2l, 2l+1)
    const int kb_l = g4 * 16;
    float bb[8];
    #pragma unroll
    for (int hh = 0; hh < 8; ++hh) bb[hh] = bbv[hh];

    float2 sA = {0.f, 0.f}, sQ2 = {0.f, 0.f};
    const int GW = gridDim.x * 4;
    for (int node = blockIdx.x * 4 + w; node < N; node += GW) {
        const int beg = offs[node], end = offs[node + 1];

        const float* qrow = Qb + (size_t)node * 128 + g4 * 4;
        float4 qv[8];
        #pragma unroll
        for (int hh = 0; hh < 8; ++hh) qv[hh] = *(const float4*)(qrow + hh * 16);

        float2 pv = {0.f, 0.f};
        float zz = 0.f;

        for (int base = beg; base < end; base += 16) {
            const int cnt = min(16, end - base);
            int ii = base + eloc;
            ii = (ii < EDG) ? ii : (EDG - 1);
            const int2 se = elist[ii];

            // per-lane eattr B-fragment (this lane's edge row, its k-octets)
            const float* ep = eattr + (size_t)se.y * 128 + g4 * 8;
            float4 ea0[4], ea1[4];
            #pragma unroll
            for (int ks = 0; ks < 4; ++ks) {
                ea0[ks] = *(const float4*)(ep + ks * 32);
                ea1[ks] = *(const float4*)(ep + ks * 32 + 4);
            }
            const float* kr = Kb + (size_t)se.x * 128 + g4 * 4;

            f32x4 acc[8], accb;
            #pragma unroll
            for (int hh = 0; hh < 8; ++hh) acc[hh] = (f32x4){0.f, 0.f, 0.f, 0.f};
            accb = (f32x4){0.f, 0.f, 0.f, 0.f};
            #pragma unroll
            for (int ks = 0; ks < 4; ++ks) {
                union { unsigned u[4]; bf16x8 v; } fr;
                fr.u[0] = cvtpk(ea0[ks].x, ea0[ks].y);
                fr.u[1] = cvtpk(ea0[ks].z, ea0[ks].w);
                fr.u[2] = cvtpk(ea1[ks].x, ea1[ks].y);
                fr.u[3] = cvtpk(ea1[ks].z, ea1[ks].w);
                const int kb = ks * 64 + kb_l;
                const bf16x8 abf = *(const bf16x8*)((char*)WbB + eloc * 256 + (kb ^ ((eloc & 7) << 4)));
                accb = __builtin_amdgcn_mfma_f32_16x16x32_bf16(abf, fr.v, accb, 0, 0, 0);
                #pragma unroll
                for (int hh = 0; hh < 8; ++hh) {
                    const int ar = hh * 16 + eloc;
                    const bf16x8 af = *(const bf16x8*)((char*)WeB + ar * 256 + (kb ^ ((ar & 7) << 4)));
                    acc[hh] = __builtin_amdgcn_mfma_f32_16x16x32_bf16(af, fr.v, acc[hh], 0, 0, 0);
                }
            }

            // score epilogue: fp32 K*Q dot vs acc, cross-lane reduce, exp
            float scv[8];
            #pragma unroll
            for (int hh = 0; hh < 8; ++hh) {
                const float4 kk = *(const float4*)(kr + hh * 16);
                const float4 qq = qv[hh];
                float m = acc[hh][0] * (kk.x * qq.x) + acc[hh][1] * (kk.y * qq.y)
                        + acc[hh][2] * (kk.z * qq.z) + acc[hh][3] * (kk.w * qq.w);
                m += __shfl_xor(m, 16);
                m += __shfl_xor(m, 32);
                const float eb = __shfl(accb[hh & 3], ((hh >> 2) << 4) | eloc);
                float sc = m * 0.25f + eb + bb[hh];
                sc = expf(fminf(fmaxf(sc, -5.f), 5.f));
                scv[hh] = (eloc < cnt) ? sc : 0.f;   // mask chunk tail
            }
            if (l < 16) {
                float4 s0 = {scv[0], scv[1], scv[2], scv[3]};
                float4 s1 = {scv[4], scv[5], scv[6], scv[7]};
                *(float4*)&scw[w][l][0] = s0;
                *(float4*)&scw[w][l][4] = s1;
                srw[w][l] = se.x;
            }
            asm volatile("s_waitcnt lgkmcnt(0)" ::: "memory");
            __builtin_amdgcn_sched_barrier(0);

            // PV: lane owns dims (2l, 2l+1); 4-deep pipelined V gathers
            int e = 0;
            for (; e + 3 < cnt; e += 4) {
                const int   s0 = srw[w][e],     s1 = srw[w][e + 1];
                const int   s2 = srw[w][e + 2], s3 = srw[w][e + 3];
                const float c0 = scw[w][e][hh_l],     c1 = scw[w][e + 1][hh_l];
                const float c2 = scw[w][e + 2][hh_l], c3 = scw[w][e + 3][hh_l];
                const float2 v0 = *(const float2*)&Vb[(size_t)s0 * 128 + 2 * l];
                const float2 v1 = *(const float2*)&Vb[(size_t)s1 * 128 + 2 * l];
                const float2 v2 = *(const float2*)&Vb[(size_t)s2 * 128 + 2 * l];
                const float2 v3 = *(const float2*)&Vb[(size_t)s3 * 128 + 2 * l];
                pv.x += v0.x * c0 + v1.x * c1 + v2.x * c2 + v3.x * c3;
                pv.y += v0.y * c0 + v1.y * c1 + v2.y * c2 + v3.y * c3;
                zz += c0 + c1 + c2 + c3;
            }
            for (; e < cnt; ++e) {
                const int   s0 = srw[w][e];
                const float c0 = scw[w][e][hh_l];
                const float2 v0 = *(const float2*)&Vb[(size_t)s0 * 128 + 2 * l];
                pv.x += v0.x * c0; pv.y += v0.y * c0;
                zz += c0;
            }
        }

        const float inv = 1.f / (zz + 1e-6f);
        const float2 hv = *(const float2*)&h[(size_t)node * 128 + 2 * l];
        float2 xv;
        xv.x = hv.x + pv.x * inv;
        xv.y = hv.y + pv.y * inv;
        *(float2*)&x[(size_t)node * 128 + 2 * l] = xv;
        sA.x += xv.x; sA.y += xv.y;
        sQ2.x += xv.x * xv.x; sQ2.y += xv.y * xv.y;
    }

    ssl[w][2 * l] = sA.x;  ssl[w][2 * l + 1] = sA.y;
    sql[w][2 * l] = sQ2.x; sql[w][2 * l + 1] = sQ2.y;
    __syncthreads();
    if (t < 128) {
        atomicAdd(&stat[t],       ssl[0][t] + ssl[1][t] + ssl[2][t] + ssl[3][t]);
        atomicAdd(&stat[128 + t], sql[0][t] + sql[1][t] + sql[2][t] + sql[3][t]);
    }
}

// ---------------------------------------------------------- BN params ------
__global__ void bn_params(const float* __restrict__ sum, const float* __restrict__ sumsq,
                          const float* __restrict__ gamma, const float* __restrict__ beta,
                          float* __restrict__ a, float* __restrict__ b, float invn)
{
    const int c = threadIdx.x;
    const float mean = sum[c] * invn;
    const float var  = sumsq[c] * invn - mean * mean;
    const float sc   = gamma[c] * rsqrtf(var + 1e-5f);
    a[c] = sc;
    b[c] = beta[c] - mean * sc;
}

// ---------------------------------------------------------------- FFN ------
__global__ __launch_bounds__(128)
void ffn_kernel(const float* __restrict__ x, const float* __restrict__ W1,
                const float* __restrict__ b1, const float* __restrict__ W2,
                const float* __restrict__ b2, const float* __restrict__ par,
                float* __restrict__ zb, float* __restrict__ stat2)
{
    __shared__ float xnl[16 * 128];
    __shared__ float hidl[16 * 256];
    const int t  = threadIdx.x;
    const int n0 = blockIdx.x * 16;

    const float4* xg4 = (const float4*)(x + (size_t)n0 * 128);
    const float4* a4  = (const float4*)par;
    const float4* bv4 = (const float4*)(par + 128);
    float4* xnl4 = (float4*)xnl;
    #pragma unroll
    for (int i = 0; i < 4; ++i) {
        const int idx = i * 128 + t;
        const float4 xv = xg4[idx];
        const float4 av = a4[idx & 31], bv = bv4[idx & 31];
        float4 r;
        r.x = xv.x * av.x + bv.x; r.y = xv.y * av.y + bv.y;
        r.z = xv.z * av.z + bv.z; r.w = xv.w * av.w + bv.w;
        xnl4[idx] = r;
    }
    __syncthreads();

    float acc0[16], acc1[16];
    #pragma unroll
    for (int n = 0; n < 16; ++n) { acc0[n] = 0.f; acc1[n] = 0.f; }
    const float* w0p = W1 + (size_t)t * 128;
    const float* w1p = W1 + (size_t)(t + 128) * 128;
    for (int kc = 0; kc < 32; ++kc) {
        const float4 w0 = *(const float4*)(w0p + kc * 4);
        const float4 w1 = *(const float4*)(w1p + kc * 4);
        #pragma unroll
        for (int n = 0; n < 16; ++n) {
            const float4 xv = *(const float4*)&xnl[n * 128 + kc * 4];
            acc0[n] += w0.x * xv.x + w0.y * xv.y + w0.z * xv.z + w0.w * xv.w;
            acc1[n] += w1.x * xv.x + w1.y * xv.y + w1.z * xv.z + w1.w * xv.w;
        }
    }
    const float bi0 = b1[t], bi1 = b1[t + 128];
    #pragma unroll
    for (int n = 0; n < 16; ++n) {
        hidl[n * 256 + t]       = fmaxf(acc0[n] + bi0, 0.f);
        hidl[n * 256 + 128 + t] = fmaxf(acc1[n] + bi1, 0.f);
    }
    __syncthreads();

    float acc2[16];
    #pragma unroll
    for (int n = 0; n < 16; ++n) acc2[n] = 0.f;
    const float* w2p = W2 + (size_t)t * 256;
    for (int kc = 0; kc < 64; ++kc) {
        const float4 w = *(const float4*)(w2p + kc * 4);
        #pragma unroll
        for (int n = 0; n < 16; ++n) {
            const float4 hv = *(const float4*)&hidl[n * 256 + kc * 4];
            acc2[n] += w.x * hv.x + w.y * hv.y + w.z * hv.z + w.w * hv.w;
        }
    }
    const float bi2 = b2[t];
    float s = 0.f, sq = 0.f;
    float* zo = zb + (size_t)n0 * 128 + t;
    #pragma unroll
    for (int n = 0; n < 16; ++n) {
        const float z = xnl[n * 128 + t] + acc2[n] + bi2;
        zo[(size_t)n * 128] = z;
        s += z; sq += z * z;
    }
    atomicAdd(&stat2[t], s);
    atomicAdd(&stat2[128 + t], sq);
}

// ---------------------------------------------------------- final BN -------
__global__ void final_bn(const float4* __restrict__ zb, const float* __restrict__ pa,
                         const float* __restrict__ pb, float4* __restrict__ out, int total4)
{
    const float4* a4 = (const float4*)pa;
    const float4* b4 = (const float4*)pb;
    const int stride = gridDim.x * blockDim.x;
    for (int i = blockIdx.x * blockDim.x + threadIdx.x; i < total4; i += stride) {
        const float4 z = zb[i];
        const float4 a = a4[i & 31], b = b4[i & 31];
        float4 r;
        r.x = z.x * a.x + b.x; r.y = z.y * a.y + b.y;
        r.z = z.z * a.z + b.z; r.w = z.w * a.w + b.w;
        out[i] = r;
    }
}

// ---------------------------------------------------------------------------
extern "C" void kernel_launch(void* const* d_in, const int* in_sizes, int n_in,
                              void* d_out, int out_size, void* d_ws, size_t ws_size,
                              hipStream_t stream)
{
    const float* h   = (const float*)d_in[0];
    const int*   ei  = (const int*)  d_in[1];
    const float* ea  = (const float*)d_in[2];
    const float* Wq  = (const float*)d_in[3];
    const float* Wk  = (const float*)d_in[4];
    const float* Wv  = (const float*)d_in[5];
    const float* We  = (const float*)d_in[6];
    const float* Wb  = (const float*)d_in[7];
    const float* bbv = (const float*)d_in[8];
    const float* g1  = (const float*)d_in[9];
    const float* be1 = (const float*)d_in[10];
    const float* W1  = (const float*)d_in[11];
    const float* b1  = (const float*)d_in[12];
    const float* W2  = (const float*)d_in[13];
    const float* b2  = (const float*)d_in[14];
    const float* g2  = (const float*)d_in[15];
    const float* be2 = (const float*)d_in[16];
    float* out = (float*)d_out;

    const int N   = in_sizes[0] / 128;
    const int EDG = in_sizes[1] / 2;
    const int NB  = (N + 1023) / 1024;
    const size_t nd = (size_t)N * 128;
    auto al8 = [](size_t v){ return (v + 7) & ~(size_t)7; };

    float* ws = (float*)d_ws;
    const size_t Qo  = 0;                            // Qb; reused as z after fused_attn
    const size_t Ko  = nd;                           // Kb
    const size_t Vo  = 2 * nd;                       // Vb
    const size_t Xo  = 3 * nd;                       // x (attn output)
    const size_t ELo = 4 * nd;                       // elist (EDG int2)
    const size_t OFo = ELo + (size_t)EDG * 2;        // offs (N+1 int)
    const size_t CUo = al8(OFo + (size_t)N + 8);     // counts (N int)
    const size_t BSo = al8(CUo + (size_t)N);         // block sums (NB int)
    const size_t BBo = al8(BSo + (size_t)NB);        // block bases (NB int)
    const size_t STo = al8(BBo + (size_t)NB);        // stats: 512 f32
    const size_t PAR = STo + 512;                    // bn params: 512 f32

    int*  cnt   = (int*)(ws + CUo);
    int*  offs  = (int*)(ws + OFo);
    int*  bsum  = (int*)(ws + BSo);
    int*  bbase = (int*)(ws + BBo);
    int2* elist = (int2*)(ws + ELo);

    hipMemsetAsync(cnt, 0, (size_t)N * sizeof(int), stream);
    hipMemsetAsync(ws + STo, 0, 512 * sizeof(float), stream);

    qkv_kernel<<<N / 16, 128, 0, stream>>>(h, Wq, Wk, Wv, ws + Qo, ws + Ko, ws + Vo);

    hist_kernel<<<1024, 256, 0, stream>>>(ei, cnt, EDG);
    scan_a<<<NB, 1024, 0, stream>>>(cnt, bsum, N);
    scan_b<<<1, 64, 0, stream>>>(bsum, bbase, offs, NB, N);
    scan_c<<<NB, 1024, 0, stream>>>(cnt, bbase, offs, N);
    scatter_kernel<<<1024, 256, 0, stream>>>(ei, offs, cnt, elist, EDG);

    fused_attn<<<768, 256, 0, stream>>>(ea, elist, offs, We, Wb, bbv,
                                        ws + Qo, ws + Ko, ws + Vo, h,
                                        ws + Xo, ws + STo, N, EDG);

    bn_params<<<1, 128, 0, stream>>>(ws + STo, ws + STo + 128, g1, be1,
                                     ws + PAR, ws + PAR + 128, 1.0f / (float)N);
    ffn_kernel<<<N / 16, 128, 0, stream>>>(ws + Xo, W1, b1, W2, b2, ws + PAR,
                                           ws + Qo, ws + STo + 256);
    bn_params<<<1, 128, 0, stream>>>(ws + STo + 256, ws + STo + 384, g2, be2,
                                     ws + PAR + 256, ws + PAR + 384, 1.0f / (float)N);
    final_bn<<<1024, 256, 0, stream>>>((const float4*)(ws + Qo), ws + PAR + 256,
                                       ws + PAR + 384, (float4*)out, N * 32);
}